// Round 2
// baseline (3401.340 us; speedup 1.0000x reference)
//
#include <hip/hip_runtime.h>
#include <hip/hip_bf16.h>

#define BB 4
#define TT 2048
#define DIM 512
#define NH 8
#define HD 64
#define NROW (BB*TT)   // 8192
#define BH (BB*NH)     // 32
#define TQ 4

typedef unsigned short u16;
typedef unsigned int u32;

static __device__ __forceinline__ float bf2f(u16 u) {
    return __uint_as_float(((u32)u) << 16);
}
static __device__ __forceinline__ u16 f2bf(float f) {
    u32 u = __float_as_uint(f);
    u32 r = (u + 0x7FFFu + ((u >> 16) & 1u)) >> 16;
    return (u16)r;
}

// dtype-generic element loads (BF=true: bf16, BF=false: f32). i = element index.
template<bool BF>
static __device__ __forceinline__ float2 ld2(const void* p, size_t i) {
    if (BF) { ushort2 v = *(const ushort2*)((const u16*)p + i);
              return make_float2(bf2f(v.x), bf2f(v.y)); }
    else    return *(const float2*)((const float*)p + i);
}
template<bool BF>
static __device__ __forceinline__ float4 ld4(const void* p, size_t i) {
    if (BF) { ushort4 v = *(const ushort4*)((const u16*)p + i);
              return make_float4(bf2f(v.x), bf2f(v.y), bf2f(v.z), bf2f(v.w)); }
    else    return *(const float4*)((const float*)p + i);
}
template<bool BF>
static __device__ __forceinline__ void st2(void* p, size_t i, float a, float b) {
    if (BF) { ushort2 o; o.x = f2bf(a); o.y = f2bf(b);
              *(ushort2*)((u16*)p + i) = o; }
    else    *(float2*)((float*)p + i) = make_float2(a, b);
}

// ---------------- Kernel 0: detect input dtype + zero atomic accumulators.
// Reads only the first 1 KB of x (safe whether x is 8 MB bf16 or 16 MB f32).
__global__ __launch_bounds__(256) void init_kernel(
    const u16* __restrict__ xraw, float* __restrict__ asq,
    u32* __restrict__ bmaxsq, int* __restrict__ flag)
{
    const int tid = threadIdx.x;
    if (tid < BH) asq[tid] = 0.0f;
    if (tid >= 32 && tid < 32 + BB) bmaxsq[tid - 32] = 0u;

    // even-index u16s: genuine values if bf16; low-mantissa noise if f32
    float v = bf2f(xraw[2 * tid]);
    float av = fabsf(v);
    int in = (av > 1e-5f && av < 1e5f) ? 1 : 0;
    __shared__ int cnt[256];
    cnt[tid] = in;
    __syncthreads();
    for (int s = 128; s > 0; s >>= 1) {
        if (tid < s) cnt[tid] += cnt[tid + s];
        __syncthreads();
    }
    if (tid == 0) *flag = (cnt[0] > 128) ? 1 : 0;   // 1 = bf16, 0 = f32
}

// ---------------- Kernel A: qkv = x @ W_qkv, scatter to q/v [b,h,t,d] f32,
// plus per-row ||x||^2 -> atomicMax per batch (uint bits, values >= 0).
template<bool BF>
__global__ __launch_bounds__(256) void qkv_kernel(
    const void* __restrict__ x, const void* __restrict__ Wqkv,
    float* __restrict__ qws, float* __restrict__ vws,
    u32* __restrict__ bmaxsq, const int* __restrict__ flag)
{
    if ((*flag != 0) != BF) return;
    const int tid = threadIdx.x;
    const int lane = tid & 63, wv = tid >> 6;
    const int row0 = blockIdx.x * 4;        // 4 rows per block
    const int b = row0 >> 11;

    __shared__ float xs[4][DIM];
    __shared__ float red[4][4];             // [wave][rr]

    float ssq[4];
    #pragma unroll
    for (int rr = 0; rr < 4; ++rr) {
        float2 xv = ld2<BF>(x, (size_t)(row0 + rr) * DIM + 2 * tid);
        xs[rr][2*tid]   = xv.x;
        xs[rr][2*tid+1] = xv.y;
        ssq[rr] = xv.x*xv.x + xv.y*xv.y;
    }
    #pragma unroll
    for (int rr = 0; rr < 4; ++rr) {
        float s = ssq[rr];
        #pragma unroll
        for (int off = 32; off > 0; off >>= 1) s += __shfl_down(s, off, 64);
        if (lane == 0) red[wv][rr] = s;
    }
    __syncthreads();
    if (tid < 4) {
        float tot = red[0][tid] + red[1][tid] + red[2][tid] + red[3][tid];
        atomicMax(&bmaxsq[b], __float_as_uint(tot));
    }

    float acc[4][4];
    #pragma unroll
    for (int rr = 0; rr < 4; ++rr)
        #pragma unroll
        for (int i = 0; i < 4; ++i) acc[rr][i] = 0.0f;

    for (int k4 = 0; k4 < DIM/4; ++k4) {
        float xb[4][4];
        #pragma unroll
        for (int rr = 0; rr < 4; ++rr) {
            float4 v4 = *(const float4*)&xs[rr][4*k4];
            xb[rr][0] = v4.x; xb[rr][1] = v4.y; xb[rr][2] = v4.z; xb[rr][3] = v4.w;
        }
        #pragma unroll
        for (int u = 0; u < 4; ++u) {
            int k = 4*k4 + u;
            float4 w = ld4<BF>(Wqkv, (size_t)k * (2*DIM) + 4*tid);
            #pragma unroll
            for (int rr = 0; rr < 4; ++rr) {
                float xv = xb[rr][u];
                acc[rr][0] += xv * w.x;
                acc[rr][1] += xv * w.y;
                acc[rr][2] += xv * w.z;
                acc[rr][3] += xv * w.w;
            }
        }
    }

    // col c = d*16 + k*8 + h  (einops 'b t (d k h)')
    #pragma unroll
    for (int i = 0; i < 4; ++i) {
        int c = 4*tid + i;
        int h = c & 7;
        int kk = (c >> 3) & 1;
        int d = c >> 4;
        float* dst = kk ? vws : qws;
        #pragma unroll
        for (int rr = 0; rr < 4; ++rr) {
            int t = (row0 & (TT-1)) + rr;
            dst[(((size_t)(b*NH + h))*TT + t)*HD + d] = acc[rr][i];
        }
    }
}

// ---------------- Kernel B: qsq[b,h,t] = sum_d q^2 ; asq[b,h] += qsq
__global__ __launch_bounds__(256) void qsq_kernel(
    const float* __restrict__ qws, float* __restrict__ qsq, float* __restrict__ asq)
{
    const int tid = threadIdx.x, lane = tid & 63, wv = tid >> 6;
    const int row = blockIdx.x * 4 + wv;   // 0..BH*TT-1
    float q = qws[(size_t)row * HD + lane];
    float s = q * q;
    #pragma unroll
    for (int off = 32; off > 0; off >>= 1) s += __shfl_down(s, off, 64);
    if (lane == 0) {
        qsq[row] = s;
        atomicAdd(&asq[row >> 11], s);
    }
}

// ---------------- Kernel C: attention, TQ rows per block, full logit rows in LDS
__global__ __launch_bounds__(256) void attn_kernel(
    const float* __restrict__ qws, const float* __restrict__ vws,
    const float* __restrict__ qsq, const float* __restrict__ asq,
    const u32* __restrict__ bmaxsq, float* __restrict__ ao)
{
    const int tid = threadIdx.x, lane = tid & 63, wv = tid >> 6;
    const int tile = blockIdx.x & (TT/TQ - 1);   // 512 tiles
    const int bh   = blockIdx.x >> 9;
    const int b = bh >> 3, h = bh & 7;
    const int t0 = tile * TQ;

    __shared__ float qt[TQ][HD];
    __shared__ float lg[TQ][TT];
    __shared__ float red[TQ][4];

    const float* qbase = qws + (size_t)bh * TT * HD;
    const float* vbase = vws + (size_t)bh * TT * HD;

    for (int idx = tid; idx < TQ*HD; idx += 256)
        qt[idx >> 6][idx & 63] = qbase[(size_t)(t0 + (idx >> 6)) * HD + (idx & 63)];

    float cs;
    {
        float a  = sqrtf(asq[bh]);
        float bm = sqrtf(__uint_as_float(bmaxsq[b]));
        cs = 100.0f / (a * bm + 1e-10f);
    }
    __syncthreads();

    // phase 1: logits (row-constant -qsq_t dropped; softmax shift-invariant)
    float lmax[TQ];
    #pragma unroll
    for (int r = 0; r < TQ; ++r) lmax[r] = -3.4e38f;
    for (int i = 0; i < TT/256; ++i) {
        int s = i*256 + tid;
        const float4* qrow = (const float4*)(qbase + (size_t)s * HD);
        float dot[TQ] = {0.f, 0.f, 0.f, 0.f};
        #pragma unroll
        for (int j = 0; j < HD/4; ++j) {
            float4 a = qrow[j];
            #pragma unroll
            for (int r = 0; r < TQ; ++r) {
                float4 w = *(const float4*)&qt[r][4*j];
                dot[r] += a.x*w.x + a.y*w.y + a.z*w.z + a.w*w.w;
            }
        }
        float qq = qsq[(size_t)bh*TT + s];
        #pragma unroll
        for (int r = 0; r < TQ; ++r) {
            float l = cs * (2.0f*dot[r] - qq);
            lg[r][s] = l;
            lmax[r] = fmaxf(lmax[r], l);
        }
    }
    #pragma unroll
    for (int r = 0; r < TQ; ++r) {
        float m = lmax[r];
        #pragma unroll
        for (int off = 32; off > 0; off >>= 1) m = fmaxf(m, __shfl_down(m, off, 64));
        if (lane == 0) red[r][wv] = m;
    }
    __syncthreads();
    float mx[TQ];
    #pragma unroll
    for (int r = 0; r < TQ; ++r)
        mx[r] = fmaxf(fmaxf(red[r][0], red[r][1]), fmaxf(red[r][2], red[r][3]));
    __syncthreads();  // before reusing red

    // phase 2: exp + sum
    float lsum[TQ] = {0.f, 0.f, 0.f, 0.f};
    for (int i = 0; i < TT/256; ++i) {
        int s = i*256 + tid;
        #pragma unroll
        for (int r = 0; r < TQ; ++r) {
            float e = __expf(lg[r][s] - mx[r]);
            lg[r][s] = e;
            lsum[r] += e;
        }
    }
    #pragma unroll
    for (int r = 0; r < TQ; ++r) {
        float s2 = lsum[r];
        #pragma unroll
        for (int off = 32; off > 0; off >>= 1) s2 += __shfl_down(s2, off, 64);
        if (lane == 0) red[r][wv] = s2;
    }
    __syncthreads();
    float inv[TQ];
    #pragma unroll
    for (int r = 0; r < TQ; ++r)
        inv[r] = 1.0f / (red[r][0] + red[r][1] + red[r][2] + red[r][3]);

    // phase 3: O = P @ V ; each wave owns a 512-wide s-range, lane = d
    float oacc[TQ] = {0.f, 0.f, 0.f, 0.f};
    const int g = wv, d = lane;
    for (int s4 = g*512; s4 < g*512 + 512; s4 += 4) {
        float v0 = vbase[(size_t)(s4+0)*HD + d];
        float v1 = vbase[(size_t)(s4+1)*HD + d];
        float v2 = vbase[(size_t)(s4+2)*HD + d];
        float v3 = vbase[(size_t)(s4+3)*HD + d];
        #pragma unroll
        for (int r = 0; r < TQ; ++r) {
            float4 p = *(const float4*)&lg[r][s4];
            oacc[r] += p.x*v0 + p.y*v1 + p.z*v2 + p.w*v3;
        }
    }
    __syncthreads();              // all lg reads done; reuse lg as obuf
    float* obuf = &lg[0][0];      // [4 groups][TQ rows][64 d] = 1024 floats
    #pragma unroll
    for (int r = 0; r < TQ; ++r) obuf[(g*TQ + r)*64 + d] = oacc[r];
    __syncthreads();
    for (int oi = tid; oi < TQ*HD; oi += 256) {
        int r = oi >> 6, dd = oi & 63;
        float sum = obuf[(0*TQ + r)*64 + dd] + obuf[(1*TQ + r)*64 + dd]
                  + obuf[(2*TQ + r)*64 + dd] + obuf[(3*TQ + r)*64 + dd];
        ao[((size_t)(b*TT + t0 + r))*DIM + h*HD + dd] = sum * inv[r];
    }
}

// ---------------- Kernel D: out = ao @ W_proj + b_proj (output in detected dtype)
template<bool BF>
__global__ __launch_bounds__(256) void proj_kernel(
    const float* __restrict__ ao, const void* __restrict__ Wp,
    const void* __restrict__ bp, void* __restrict__ out,
    const int* __restrict__ flag)
{
    if ((*flag != 0) != BF) return;
    const int tid = threadIdx.x;
    const int row0 = blockIdx.x * 4;
    __shared__ float xs[4][DIM];

    #pragma unroll
    for (int rr = 0; rr < 4; ++rr) {
        float2 v = ((const float2*)(ao + (size_t)(row0 + rr) * DIM))[tid];
        xs[rr][2*tid]   = v.x;
        xs[rr][2*tid+1] = v.y;
    }
    __syncthreads();

    float acc[4][2];
    #pragma unroll
    for (int rr = 0; rr < 4; ++rr) { acc[rr][0] = 0.f; acc[rr][1] = 0.f; }

    for (int k4 = 0; k4 < DIM/4; ++k4) {
        float xb[4][4];
        #pragma unroll
        for (int rr = 0; rr < 4; ++rr) {
            float4 v4 = *(const float4*)&xs[rr][4*k4];
            xb[rr][0] = v4.x; xb[rr][1] = v4.y; xb[rr][2] = v4.z; xb[rr][3] = v4.w;
        }
        #pragma unroll
        for (int u = 0; u < 4; ++u) {
            int k = 4*k4 + u;
            float2 w = ld2<BF>(Wp, (size_t)k * DIM + 2*tid);
            #pragma unroll
            for (int rr = 0; rr < 4; ++rr) {
                acc[rr][0] += xb[rr][u] * w.x;
                acc[rr][1] += xb[rr][u] * w.y;
            }
        }
    }

    float2 bb = ld2<BF>(bp, 2*tid);
    #pragma unroll
    for (int rr = 0; rr < 4; ++rr) {
        st2<BF>(out, (size_t)(row0 + rr) * DIM + 2*tid,
                acc[rr][0] + bb.x, acc[rr][1] + bb.y);
    }
}

extern "C" void kernel_launch(void* const* d_in, const int* in_sizes, int n_in,
                              void* d_out, int out_size, void* d_ws, size_t ws_size,
                              hipStream_t stream)
{
    const void* x     = d_in[0];   // [4,2048,512]
    const void* Wqkv  = d_in[1];   // [512,1024]
    const void* Wproj = d_in[2];   // [512,512]
    const void* bproj = d_in[3];   // [512]

    char* ws = (char*)d_ws;
    const size_t MB = 1024*1024;
    float* qws = (float*)(ws);                        // 16 MB  [b,h,t,d] f32
    float* vws = (float*)(ws + 16*MB);                // 16 MB
    float* ao  = (float*)(ws + 32*MB);                // 16 MB  [b,t,dim] f32
    float* qsq = (float*)(ws + 48*MB);                // 256 KB [b,h,t]
    float* asq = (float*)(ws + 48*MB + 262144);       // 128 B  [b,h]
    u32* bmaxsq = (u32*)(ws + 48*MB + 262144 + 128);  // 16 B   [b]
    int* flag   = (int*)(ws + 48*MB + 262144 + 192);  // 4 B

    (void)in_sizes; (void)n_in; (void)out_size; (void)ws_size;

    init_kernel<<<1, 256, 0, stream>>>((const u16*)x, asq, bmaxsq, flag);

    qkv_kernel<true>  <<<NROW/4, 256, 0, stream>>>(x, Wqkv, qws, vws, bmaxsq, flag);
    qkv_kernel<false> <<<NROW/4, 256, 0, stream>>>(x, Wqkv, qws, vws, bmaxsq, flag);

    qsq_kernel <<<BH*TT/4, 256, 0, stream>>>(qws, qsq, asq);

    attn_kernel<<<BH*(TT/TQ), 256, 0, stream>>>(qws, vws, qsq, asq, bmaxsq, ao);

    proj_kernel<true>  <<<NROW/4, 256, 0, stream>>>(ao, Wproj, bproj, d_out, flag);
    proj_kernel<false> <<<NROW/4, 256, 0, stream>>>(ao, Wproj, bproj, d_out, flag);
}

// Round 3
// 1153.972 us; speedup vs baseline: 2.9475x; 2.9475x over previous
//
#include <hip/hip_runtime.h>
#include <hip/hip_bf16.h>

#define BB 4
#define TT 2048
#define DIM 512
#define NH 8
#define HD 64
#define NROW (BB*TT)   // 8192
#define BH (BB*NH)     // 32

typedef unsigned short u16;
typedef unsigned int u32;
typedef __attribute__((ext_vector_type(8))) short bf16x8;   // 8 bf16 = 4 VGPRs
typedef __attribute__((ext_vector_type(4))) float f32x4;
typedef __attribute__((ext_vector_type(4))) unsigned short u16x4;

static __device__ __forceinline__ float bf2f(u16 u) {
    return __uint_as_float(((u32)u) << 16);
}
static __device__ __forceinline__ u16 f2bf(float f) {
    u32 u = __float_as_uint(f);
    u32 r = (u + 0x7FFFu + ((u >> 16) & 1u)) >> 16;
    return (u16)r;
}

template<bool BF>
static __device__ __forceinline__ float2 ld2(const void* p, size_t i) {
    if (BF) { ushort2 v = *(const ushort2*)((const u16*)p + i);
              return make_float2(bf2f(v.x), bf2f(v.y)); }
    else    return *(const float2*)((const float*)p + i);
}
template<bool BF>
static __device__ __forceinline__ float4 ld4(const void* p, size_t i) {
    if (BF) { ushort4 v = *(const ushort4*)((const u16*)p + i);
              return make_float4(bf2f(v.x), bf2f(v.y), bf2f(v.z), bf2f(v.w)); }
    else    return *(const float4*)((const float*)p + i);
}
template<bool BF>
static __device__ __forceinline__ void st2(void* p, size_t i, float a, float b) {
    if (BF) { ushort2 o; o.x = f2bf(a); o.y = f2bf(b);
              *(ushort2*)((u16*)p + i) = o; }
    else    *(float2*)((float*)p + i) = make_float2(a, b);
}

// ---------------- Kernel 0: detect input dtype + zero accumulators
__global__ __launch_bounds__(256) void init_kernel(
    const u16* __restrict__ xraw, float* __restrict__ asq,
    u32* __restrict__ bmaxsq, int* __restrict__ flag)
{
    const int tid = threadIdx.x;
    if (tid < BH) asq[tid] = 0.0f;
    if (tid >= 32 && tid < 32 + BB) bmaxsq[tid - 32] = 0u;

    float v = bf2f(xraw[2 * tid]);
    float av = fabsf(v);
    int in = (av > 1e-5f && av < 1e5f) ? 1 : 0;
    __shared__ int cnt[256];
    cnt[tid] = in;
    __syncthreads();
    for (int s = 128; s > 0; s >>= 1) {
        if (tid < s) cnt[tid] += cnt[tid + s];
        __syncthreads();
    }
    if (tid == 0) *flag = (cnt[0] > 128) ? 1 : 0;   // 1 = bf16, 0 = f32
}

// ---------------- Kernel A: qkv = x @ W_qkv -> q bf16 [b,h,t,d], v bf16 [b,h,d,t]
// plus per-row ||x||^2 -> atomicMax per batch.
template<bool BF>
__global__ __launch_bounds__(256) void qkv_kernel(
    const void* __restrict__ x, const void* __restrict__ Wqkv,
    u16* __restrict__ q16, u16* __restrict__ vt16,
    u32* __restrict__ bmaxsq, const int* __restrict__ flag)
{
    if ((*flag != 0) != BF) return;
    const int tid = threadIdx.x;
    const int lane = tid & 63, wv = tid >> 6;
    const int row0 = blockIdx.x * 4;
    const int b = row0 >> 11;
    const int t0g = row0 & (TT - 1);

    __shared__ float xs[4][DIM];
    __shared__ float red[4][4];

    float ssq[4];
    #pragma unroll
    for (int rr = 0; rr < 4; ++rr) {
        float2 xv = ld2<BF>(x, (size_t)(row0 + rr) * DIM + 2 * tid);
        xs[rr][2*tid]   = xv.x;
        xs[rr][2*tid+1] = xv.y;
        ssq[rr] = xv.x*xv.x + xv.y*xv.y;
    }
    #pragma unroll
    for (int rr = 0; rr < 4; ++rr) {
        float s = ssq[rr];
        #pragma unroll
        for (int off = 32; off > 0; off >>= 1) s += __shfl_down(s, off, 64);
        if (lane == 0) red[wv][rr] = s;
    }
    __syncthreads();
    if (tid < 4) {
        float tot = red[0][tid] + red[1][tid] + red[2][tid] + red[3][tid];
        atomicMax(&bmaxsq[b], __float_as_uint(tot));
    }

    float acc[4][4];
    #pragma unroll
    for (int rr = 0; rr < 4; ++rr)
        #pragma unroll
        for (int i = 0; i < 4; ++i) acc[rr][i] = 0.0f;

    for (int k4 = 0; k4 < DIM/4; ++k4) {
        float xb[4][4];
        #pragma unroll
        for (int rr = 0; rr < 4; ++rr) {
            float4 v4 = *(const float4*)&xs[rr][4*k4];
            xb[rr][0] = v4.x; xb[rr][1] = v4.y; xb[rr][2] = v4.z; xb[rr][3] = v4.w;
        }
        #pragma unroll
        for (int u = 0; u < 4; ++u) {
            int k = 4*k4 + u;
            float4 w = ld4<BF>(Wqkv, (size_t)k * (2*DIM) + 4*tid);
            #pragma unroll
            for (int rr = 0; rr < 4; ++rr) {
                float xv = xb[rr][u];
                acc[rr][0] += xv * w.x;
                acc[rr][1] += xv * w.y;
                acc[rr][2] += xv * w.z;
                acc[rr][3] += xv * w.w;
            }
        }
    }

    // col c = 4*tid+i : h = 4*(tid&1)+i, kk = (tid>>1)&1, d = tid>>2
    const int d = tid >> 2;
    const int hbase = 4 * (tid & 1);
    if (((tid >> 1) & 1) == 0) {
        // q: [b,h,t,d] bf16 (scattered u16 stores)
        #pragma unroll
        for (int i = 0; i < 4; ++i) {
            int h = hbase + i;
            u16* dst = q16 + ((size_t)(b*NH + h)*TT + t0g)*HD + d;
            #pragma unroll
            for (int rr = 0; rr < 4; ++rr) dst[(size_t)rr * HD] = f2bf(acc[rr][i]);
        }
    } else {
        // v: [b,h,d,t] bf16 (4 t's packed)
        #pragma unroll
        for (int i = 0; i < 4; ++i) {
            int h = hbase + i;
            u16x4 pk;
            pk.x = f2bf(acc[0][i]); pk.y = f2bf(acc[1][i]);
            pk.z = f2bf(acc[2][i]); pk.w = f2bf(acc[3][i]);
            *(u16x4*)(vt16 + ((size_t)(b*NH + h)*HD + d)*TT + t0g) = pk;
        }
    }
}

// ---------------- Kernel B: qsq[b,h,t] = sum_d q^2 ; asq[b,h] += qsq
__global__ __launch_bounds__(256) void qsq_kernel(
    const u16* __restrict__ q16, float* __restrict__ qsq, float* __restrict__ asq)
{
    const int tid = threadIdx.x, lane = tid & 63, wv = tid >> 6;
    const int row = blockIdx.x * 4 + wv;
    float q = bf2f(q16[(size_t)row * HD + lane]);
    float s = q * q;
    #pragma unroll
    for (int off = 32; off > 0; off >>= 1) s += __shfl_down(s, off, 64);
    if (lane == 0) {
        qsq[row] = s;
        atomicAdd(&asq[row >> 11], s);
    }
}

// ---------------- Kernel C: flash-style MFMA attention.
// Block = 4 waves, 64 q-rows (16/wave). Iterate s in tiles of 64.
#define LDK 72   // padded LDS row stride (u16 elems), keeps 16B alignment
__global__ __launch_bounds__(256) void attn_kernel(
    const u16* __restrict__ q16, const u16* __restrict__ vt16,
    const float* __restrict__ qsq, const float* __restrict__ asq,
    const u32* __restrict__ bmaxsq, float* __restrict__ ao)
{
    const int tid = threadIdx.x;
    const int lane = tid & 63, w = tid >> 6;
    const int li = lane & 15, quad = lane >> 4;
    const int bh = blockIdx.x >> 5;       // 32
    const int qtile = blockIdx.x & 31;    // 32 tiles of 64 rows
    const int b = bh >> 3, h = bh & 7;

    __shared__ __align__(16) u16 ks[64 * LDK];      // K tile  [s][d]
    __shared__ __align__(16) u16 vt[64 * LDK];      // V^T tile [d][s]
    __shared__ __align__(16) u16 ps[4 * 16 * LDK];  // per-wave P tile [qrow][s]

    const u16* qg = q16  + (size_t)bh * TT * HD;    // [t][d]
    const u16* vg = vt16 + (size_t)bh * HD * TT;    // [d][t]
    const float* qsqg = qsq + (size_t)bh * TT;

    float cs;
    {
        float a  = sqrtf(asq[bh]);
        float bm = sqrtf(__uint_as_float(bmaxsq[b]));
        cs = 100.0f / (a * bm + 1e-10f);
    }
    const float c2 = 2.0f * cs;

    // Q A-frags, held in regs for whole kernel
    const int qt0w = qtile * 64 + w * 16;
    const u16* qr = qg + (size_t)(qt0w + li) * HD + quad * 8;
    bf16x8 a0 = *(const bf16x8*)qr;
    bf16x8 a1 = *(const bf16x8*)(qr + 32);

    float m_run[4] = {-1e30f, -1e30f, -1e30f, -1e30f};
    float l_run[4] = {0.f, 0.f, 0.f, 0.f};
    f32x4 oacc[4];
    #pragma unroll
    for (int dj = 0; dj < 4; ++dj) oacc[dj] = f32x4{0.f, 0.f, 0.f, 0.f};

    for (int s0 = 0; s0 < TT; s0 += 64) {
        __syncthreads();   // previous iter's LDS reads complete
        #pragma unroll
        for (int it = 0; it < 2; ++it) {
            int u = it * 256 + tid;        // 512 units of 8 elems
            int r = u >> 3, c = u & 7;
            *(bf16x8*)&ks[r*LDK + c*8] =
                *(const bf16x8*)(qg + (size_t)s0*HD + (size_t)u*8);
            *(bf16x8*)&vt[r*LDK + c*8] =
                *(const bf16x8*)(vg + (size_t)r*TT + s0 + c*8);
        }
        __syncthreads();   // staging visible

        // ---- S = 2cs * Q K^T - cs*qsq_col  (row-constant term dropped)
        float lg[4][4];
        #pragma unroll
        for (int cj = 0; cj < 4; ++cj) {
            const u16* kr = &ks[(cj*16 + li)*LDK + quad*8];
            bf16x8 b0 = *(const bf16x8*)kr;
            bf16x8 b1 = *(const bf16x8*)(kr + 32);
            f32x4 acc = f32x4{0.f, 0.f, 0.f, 0.f};
            acc = __builtin_amdgcn_mfma_f32_16x16x32_bf16(a0, b0, acc, 0, 0, 0);
            acc = __builtin_amdgcn_mfma_f32_16x16x32_bf16(a1, b1, acc, 0, 0, 0);
            float sq = cs * qsqg[s0 + cj*16 + li];
            #pragma unroll
            for (int r = 0; r < 4; ++r) lg[cj][r] = c2 * acc[r] - sq;
        }

        // ---- online softmax (row stats across 16 lanes of quad)
        float mt[4];
        #pragma unroll
        for (int r = 0; r < 4; ++r)
            mt[r] = fmaxf(fmaxf(lg[0][r], lg[1][r]), fmaxf(lg[2][r], lg[3][r]));
        #pragma unroll
        for (int off = 1; off < 16; off <<= 1)
            #pragma unroll
            for (int r = 0; r < 4; ++r)
                mt[r] = fmaxf(mt[r], __shfl_xor(mt[r], off, 64));
        float al[4];
        #pragma unroll
        for (int r = 0; r < 4; ++r) {
            float mn = fmaxf(m_run[r], mt[r]);
            al[r] = __expf(m_run[r] - mn);
            m_run[r] = mn;
        }
        float ssum[4] = {0.f, 0.f, 0.f, 0.f};
        #pragma unroll
        for (int cj = 0; cj < 4; ++cj)
            #pragma unroll
            for (int r = 0; r < 4; ++r) {
                float p = __expf(lg[cj][r] - m_run[r]);
                ssum[r] += p;
                ps[w*16*LDK + (quad*4 + r)*LDK + cj*16 + li] = f2bf(p);
            }
        #pragma unroll
        for (int off = 1; off < 16; off <<= 1)
            #pragma unroll
            for (int r = 0; r < 4; ++r)
                ssum[r] += __shfl_xor(ssum[r], off, 64);
        #pragma unroll
        for (int r = 0; r < 4; ++r) l_run[r] = l_run[r]*al[r] + ssum[r];
        #pragma unroll
        for (int dj = 0; dj < 4; ++dj)
            #pragma unroll
            for (int r = 0; r < 4; ++r) oacc[dj][r] *= al[r];

        // ---- O += P V  (P read back in A-layout; wave-private ps region)
        #pragma unroll
        for (int kj = 0; kj < 2; ++kj) {
            bf16x8 ap = *(const bf16x8*)&ps[w*16*LDK + li*LDK + kj*32 + quad*8];
            #pragma unroll
            for (int dj = 0; dj < 4; ++dj) {
                bf16x8 bv = *(const bf16x8*)&vt[(dj*16 + li)*LDK + kj*32 + quad*8];
                oacc[dj] = __builtin_amdgcn_mfma_f32_16x16x32_bf16(ap, bv, oacc[dj], 0, 0, 0);
            }
        }
    }

    float inv[4];
    #pragma unroll
    for (int r = 0; r < 4; ++r) inv[r] = 1.0f / l_run[r];
    #pragma unroll
    for (int dj = 0; dj < 4; ++dj)
        #pragma unroll
        for (int r = 0; r < 4; ++r) {
            int t = qt0w + quad*4 + r;
            ao[((size_t)(b*TT + t))*DIM + h*HD + dj*16 + li] = oacc[dj][r] * inv[r];
        }
}

// ---------------- Kernel D: out = ao @ W_proj + b_proj
template<bool BF>
__global__ __launch_bounds__(256) void proj_kernel(
    const float* __restrict__ ao, const void* __restrict__ Wp,
    const void* __restrict__ bp, void* __restrict__ out,
    const int* __restrict__ flag)
{
    if ((*flag != 0) != BF) return;
    const int tid = threadIdx.x;
    const int row0 = blockIdx.x * 4;
    __shared__ float xs[4][DIM];

    #pragma unroll
    for (int rr = 0; rr < 4; ++rr) {
        float2 v = ((const float2*)(ao + (size_t)(row0 + rr) * DIM))[tid];
        xs[rr][2*tid]   = v.x;
        xs[rr][2*tid+1] = v.y;
    }
    __syncthreads();

    float acc[4][2];
    #pragma unroll
    for (int rr = 0; rr < 4; ++rr) { acc[rr][0] = 0.f; acc[rr][1] = 0.f; }

    for (int k4 = 0; k4 < DIM/4; ++k4) {
        float xb[4][4];
        #pragma unroll
        for (int rr = 0; rr < 4; ++rr) {
            float4 v4 = *(const float4*)&xs[rr][4*k4];
            xb[rr][0] = v4.x; xb[rr][1] = v4.y; xb[rr][2] = v4.z; xb[rr][3] = v4.w;
        }
        #pragma unroll
        for (int u = 0; u < 4; ++u) {
            int k = 4*k4 + u;
            float2 w = ld2<BF>(Wp, (size_t)k * DIM + 2*tid);
            #pragma unroll
            for (int rr = 0; rr < 4; ++rr) {
                acc[rr][0] += xb[rr][u] * w.x;
                acc[rr][1] += xb[rr][u] * w.y;
            }
        }
    }

    float2 bb = ld2<BF>(bp, 2*tid);
    #pragma unroll
    for (int rr = 0; rr < 4; ++rr) {
        st2<BF>(out, (size_t)(row0 + rr) * DIM + 2*tid,
                acc[rr][0] + bb.x, acc[rr][1] + bb.y);
    }
}

extern "C" void kernel_launch(void* const* d_in, const int* in_sizes, int n_in,
                              void* d_out, int out_size, void* d_ws, size_t ws_size,
                              hipStream_t stream)
{
    const void* x     = d_in[0];
    const void* Wqkv  = d_in[1];
    const void* Wproj = d_in[2];
    const void* bproj = d_in[3];

    char* ws = (char*)d_ws;
    const size_t MB = 1024*1024;
    u16*   q16  = (u16*)(ws);                          // 8 MB  [b,h,t,d] bf16
    u16*   vt16 = (u16*)(ws + 8*MB);                   // 8 MB  [b,h,d,t] bf16
    float* ao   = (float*)(ws + 16*MB);                // 16 MB [b,t,dim] f32
    float* qsq  = (float*)(ws + 32*MB);                // 256 KB
    float* asq  = (float*)(ws + 32*MB + 262144);       // 128 B
    u32* bmaxsq = (u32*)(ws + 32*MB + 262144 + 128);   // 16 B
    int* flag   = (int*)(ws + 32*MB + 262144 + 192);   // 4 B

    (void)in_sizes; (void)n_in; (void)out_size; (void)ws_size;

    init_kernel<<<1, 256, 0, stream>>>((const u16*)x, asq, bmaxsq, flag);

    qkv_kernel<true>  <<<NROW/4, 256, 0, stream>>>(x, Wqkv, q16, vt16, bmaxsq, flag);
    qkv_kernel<false> <<<NROW/4, 256, 0, stream>>>(x, Wqkv, q16, vt16, bmaxsq, flag);

    qsq_kernel <<<BH*TT/4, 256, 0, stream>>>(q16, qsq, asq);

    attn_kernel<<<BH*32, 256, 0, stream>>>(q16, vt16, qsq, asq, bmaxsq, ao);

    proj_kernel<true>  <<<NROW/4, 256, 0, stream>>>(ao, Wproj, bproj, d_out, flag);
    proj_kernel<false> <<<NROW/4, 256, 0, stream>>>(ao, Wproj, bproj, d_out, flag);
}

// Round 4
// 500.303 us; speedup vs baseline: 6.7986x; 2.3065x over previous
//
#include <hip/hip_runtime.h>
#include <hip/hip_bf16.h>

#define BB 4
#define TT 2048
#define DIM 512
#define NH 8
#define HD 64
#define NROW (BB*TT)   // 8192
#define BH (BB*NH)     // 32

typedef unsigned short u16;
typedef unsigned int u32;
typedef __attribute__((ext_vector_type(8))) short bf16x8;   // 8 bf16 = 4 VGPRs
typedef __attribute__((ext_vector_type(8))) unsigned short u16x8;
typedef __attribute__((ext_vector_type(4))) float f32x4;
typedef __attribute__((ext_vector_type(4))) unsigned short u16x4;

static __device__ __forceinline__ float bf2f(u16 u) {
    return __uint_as_float(((u32)u) << 16);
}
static __device__ __forceinline__ u16 f2bf(float f) {
    u32 u = __float_as_uint(f);
    u32 r = (u + 0x7FFFu + ((u >> 16) & 1u)) >> 16;
    return (u16)r;
}

template<bool BF>
static __device__ __forceinline__ float2 ld2(const void* p, size_t i) {
    if (BF) { ushort2 v = *(const ushort2*)((const u16*)p + i);
              return make_float2(bf2f(v.x), bf2f(v.y)); }
    else    return *(const float2*)((const float*)p + i);
}
template<bool BF>
static __device__ __forceinline__ float4 ld4(const void* p, size_t i) {
    if (BF) { ushort4 v = *(const ushort4*)((const u16*)p + i);
              return make_float4(bf2f(v.x), bf2f(v.y), bf2f(v.z), bf2f(v.w)); }
    else    return *(const float4*)((const float*)p + i);
}
template<bool BF>
static __device__ __forceinline__ void st2(void* p, size_t i, float a, float b) {
    if (BF) { ushort2 o; o.x = f2bf(a); o.y = f2bf(b);
              *(ushort2*)((u16*)p + i) = o; }
    else    *(float2*)((float*)p + i) = make_float2(a, b);
}

// ---------------- Kernel 0: detect input dtype + zero accumulators
__global__ __launch_bounds__(256) void init_kernel(
    const u16* __restrict__ xraw, float* __restrict__ asq,
    u32* __restrict__ bmaxsq, int* __restrict__ flag)
{
    const int tid = threadIdx.x;
    if (tid < BH) asq[tid] = 0.0f;
    if (tid >= 32 && tid < 32 + BB) bmaxsq[tid - 32] = 0u;

    float v = bf2f(xraw[2 * tid]);
    float av = fabsf(v);
    int in = (av > 1e-5f && av < 1e5f) ? 1 : 0;
    __shared__ int cnt[256];
    cnt[tid] = in;
    __syncthreads();
    for (int s = 128; s > 0; s >>= 1) {
        if (tid < s) cnt[tid] += cnt[tid + s];
        __syncthreads();
    }
    if (tid == 0) *flag = (cnt[0] > 128) ? 1 : 0;   // 1 = bf16, 0 = f32
}

// ---------------- Kernel A: qkv = x @ W_qkv -> q bf16 [b,h,t,d], v bf16 [b,h,d,t]
// plus per-row ||x||^2 -> (block max) -> single atomicMax per block.
template<bool BF>
__global__ __launch_bounds__(256) void qkv_kernel(
    const void* __restrict__ x, const void* __restrict__ Wqkv,
    u16* __restrict__ q16, u16* __restrict__ vt16,
    u32* __restrict__ bmaxsq, const int* __restrict__ flag)
{
    if ((*flag != 0) != BF) return;
    const int tid = threadIdx.x;
    const int lane = tid & 63, wv = tid >> 6;
    const int row0 = blockIdx.x * 4;
    const int b = row0 >> 11;
    const int t0g = row0 & (TT - 1);

    __shared__ float xs[4][DIM];
    __shared__ float red[4][4];

    float ssq[4];
    #pragma unroll
    for (int rr = 0; rr < 4; ++rr) {
        float2 xv = ld2<BF>(x, (size_t)(row0 + rr) * DIM + 2 * tid);
        xs[rr][2*tid]   = xv.x;
        xs[rr][2*tid+1] = xv.y;
        ssq[rr] = xv.x*xv.x + xv.y*xv.y;
    }
    #pragma unroll
    for (int rr = 0; rr < 4; ++rr) {
        float s = ssq[rr];
        #pragma unroll
        for (int off = 32; off > 0; off >>= 1) s += __shfl_down(s, off, 64);
        if (lane == 0) red[wv][rr] = s;
    }
    __syncthreads();
    if (tid == 0) {
        float mx = 0.0f;
        #pragma unroll
        for (int rr = 0; rr < 4; ++rr) {
            float tot = red[0][rr] + red[1][rr] + red[2][rr] + red[3][rr];
            mx = fmaxf(mx, tot);
        }
        atomicMax(&bmaxsq[b], __float_as_uint(mx));  // 1 atomic per block
    }

    float acc[4][4];
    #pragma unroll
    for (int rr = 0; rr < 4; ++rr)
        #pragma unroll
        for (int i = 0; i < 4; ++i) acc[rr][i] = 0.0f;

    for (int k4 = 0; k4 < DIM/4; ++k4) {
        float xb[4][4];
        #pragma unroll
        for (int rr = 0; rr < 4; ++rr) {
            float4 v4 = *(const float4*)&xs[rr][4*k4];
            xb[rr][0] = v4.x; xb[rr][1] = v4.y; xb[rr][2] = v4.z; xb[rr][3] = v4.w;
        }
        #pragma unroll
        for (int u = 0; u < 4; ++u) {
            int k = 4*k4 + u;
            float4 w = ld4<BF>(Wqkv, (size_t)k * (2*DIM) + 4*tid);
            #pragma unroll
            for (int rr = 0; rr < 4; ++rr) {
                float xv = xb[rr][u];
                acc[rr][0] += xv * w.x;
                acc[rr][1] += xv * w.y;
                acc[rr][2] += xv * w.z;
                acc[rr][3] += xv * w.w;
            }
        }
    }

    // col c = 4*tid+i : h = 4*(tid&1)+i, kk = (tid>>1)&1, d = tid>>2
    const int d = tid >> 2;
    const int hbase = 4 * (tid & 1);
    if (((tid >> 1) & 1) == 0) {
        // q: [b,h,t,d] bf16
        #pragma unroll
        for (int i = 0; i < 4; ++i) {
            int h = hbase + i;
            u16* dst = q16 + ((size_t)(b*NH + h)*TT + t0g)*HD + d;
            #pragma unroll
            for (int rr = 0; rr < 4; ++rr) dst[(size_t)rr * HD] = f2bf(acc[rr][i]);
        }
    } else {
        // v: [b,h,d,t] bf16 (4 t's packed)
        #pragma unroll
        for (int i = 0; i < 4; ++i) {
            int h = hbase + i;
            u16x4 pk;
            pk.x = f2bf(acc[0][i]); pk.y = f2bf(acc[1][i]);
            pk.z = f2bf(acc[2][i]); pk.w = f2bf(acc[3][i]);
            *(u16x4*)(vt16 + ((size_t)(b*NH + h)*HD + d)*TT + t0g) = pk;
        }
    }
}

// ---------------- Kernel B: qsq[b,h,t] = sum_d q^2 ; asq[b,h] = sum_t qsq
// 8 blocks per bh, 256 rows per block, 8 lanes per row (16B loads),
// ONE atomicAdd per block (256 total -- was 65536).
__global__ __launch_bounds__(256) void qsq_kernel(
    const u16* __restrict__ q16, float* __restrict__ qsq, float* __restrict__ asq)
{
    const int tid = threadIdx.x;
    const int bh = blockIdx.x >> 3;
    const int r0 = (blockIdx.x & 7) * 256;
    const u16* qb = q16 + ((size_t)bh * TT + r0) * HD;

    float tot = 0.0f;
    #pragma unroll
    for (int i = 0; i < 8; ++i) {
        int row = i * 32 + (tid >> 3);
        u16x8 v = *(const u16x8*)(qb + (size_t)row * HD + (tid & 7) * 8);
        float s = 0.0f;
        #pragma unroll
        for (int j = 0; j < 8; ++j) { float f = bf2f(v[j]); s += f * f; }
        tot += s;
        #pragma unroll
        for (int off = 1; off < 8; off <<= 1) s += __shfl_xor(s, off, 64);
        if ((tid & 7) == 0) qsq[(size_t)bh * TT + r0 + row] = s;
    }
    // block reduction of tot
    __shared__ float red[4];
    #pragma unroll
    for (int off = 32; off > 0; off >>= 1) tot += __shfl_down(tot, off, 64);
    if ((tid & 63) == 0) red[tid >> 6] = tot;
    __syncthreads();
    if (tid == 0) atomicAdd(&asq[bh], red[0] + red[1] + red[2] + red[3]);
}

// ---------------- Kernel C: flash-style MFMA attention.
#define LDK 72   // padded LDS row stride (u16 elems), keeps 16B alignment
__global__ __launch_bounds__(256) void attn_kernel(
    const u16* __restrict__ q16, const u16* __restrict__ vt16,
    const float* __restrict__ qsq, const float* __restrict__ asq,
    const u32* __restrict__ bmaxsq, float* __restrict__ ao)
{
    const int tid = threadIdx.x;
    const int lane = tid & 63, w = tid >> 6;
    const int li = lane & 15, quad = lane >> 4;
    const int bh = blockIdx.x >> 5;       // 32
    const int qtile = blockIdx.x & 31;    // 32 tiles of 64 rows
    const int b = bh >> 3, h = bh & 7;

    __shared__ __align__(16) u16 ks[64 * LDK];      // K tile  [s][d]
    __shared__ __align__(16) u16 vt[64 * LDK];      // V^T tile [d][s]
    __shared__ __align__(16) u16 ps[4 * 16 * LDK];  // per-wave P tile [qrow][s]

    const u16* qg = q16  + (size_t)bh * TT * HD;    // [t][d]
    const u16* vg = vt16 + (size_t)bh * HD * TT;    // [d][t]
    const float* qsqg = qsq + (size_t)bh * TT;

    float cs;
    {
        float a  = sqrtf(asq[bh]);
        float bm = sqrtf(__uint_as_float(bmaxsq[b]));
        cs = 100.0f / (a * bm + 1e-10f);
    }
    const float c2 = 2.0f * cs;

    const int qt0w = qtile * 64 + w * 16;
    const u16* qr = qg + (size_t)(qt0w + li) * HD + quad * 8;
    bf16x8 a0 = *(const bf16x8*)qr;
    bf16x8 a1 = *(const bf16x8*)(qr + 32);

    float m_run[4] = {-1e30f, -1e30f, -1e30f, -1e30f};
    float l_run[4] = {0.f, 0.f, 0.f, 0.f};
    f32x4 oacc[4];
    #pragma unroll
    for (int dj = 0; dj < 4; ++dj) oacc[dj] = f32x4{0.f, 0.f, 0.f, 0.f};

    for (int s0 = 0; s0 < TT; s0 += 64) {
        __syncthreads();
        #pragma unroll
        for (int it = 0; it < 2; ++it) {
            int u = it * 256 + tid;
            int r = u >> 3, c = u & 7;
            *(bf16x8*)&ks[r*LDK + c*8] =
                *(const bf16x8*)(qg + (size_t)s0*HD + (size_t)u*8);
            *(bf16x8*)&vt[r*LDK + c*8] =
                *(const bf16x8*)(vg + (size_t)r*TT + s0 + c*8);
        }
        __syncthreads();

        float lg[4][4];
        #pragma unroll
        for (int cj = 0; cj < 4; ++cj) {
            const u16* kr = &ks[(cj*16 + li)*LDK + quad*8];
            bf16x8 b0 = *(const bf16x8*)kr;
            bf16x8 b1 = *(const bf16x8*)(kr + 32);
            f32x4 acc = f32x4{0.f, 0.f, 0.f, 0.f};
            acc = __builtin_amdgcn_mfma_f32_16x16x32_bf16(a0, b0, acc, 0, 0, 0);
            acc = __builtin_amdgcn_mfma_f32_16x16x32_bf16(a1, b1, acc, 0, 0, 0);
            float sq = cs * qsqg[s0 + cj*16 + li];
            #pragma unroll
            for (int r = 0; r < 4; ++r) lg[cj][r] = c2 * acc[r] - sq;
        }

        float mt[4];
        #pragma unroll
        for (int r = 0; r < 4; ++r)
            mt[r] = fmaxf(fmaxf(lg[0][r], lg[1][r]), fmaxf(lg[2][r], lg[3][r]));
        #pragma unroll
        for (int off = 1; off < 16; off <<= 1)
            #pragma unroll
            for (int r = 0; r < 4; ++r)
                mt[r] = fmaxf(mt[r], __shfl_xor(mt[r], off, 64));
        float al[4];
        #pragma unroll
        for (int r = 0; r < 4; ++r) {
            float mn = fmaxf(m_run[r], mt[r]);
            al[r] = __expf(m_run[r] - mn);
            m_run[r] = mn;
        }
        float ssum[4] = {0.f, 0.f, 0.f, 0.f};
        #pragma unroll
        for (int cj = 0; cj < 4; ++cj)
            #pragma unroll
            for (int r = 0; r < 4; ++r) {
                float p = __expf(lg[cj][r] - m_run[r]);
                ssum[r] += p;
                ps[w*16*LDK + (quad*4 + r)*LDK + cj*16 + li] = f2bf(p);
            }
        #pragma unroll
        for (int off = 1; off < 16; off <<= 1)
            #pragma unroll
            for (int r = 0; r < 4; ++r)
                ssum[r] += __shfl_xor(ssum[r], off, 64);
        #pragma unroll
        for (int r = 0; r < 4; ++r) l_run[r] = l_run[r]*al[r] + ssum[r];
        #pragma unroll
        for (int dj = 0; dj < 4; ++dj)
            #pragma unroll
            for (int r = 0; r < 4; ++r) oacc[dj][r] *= al[r];

        #pragma unroll
        for (int kj = 0; kj < 2; ++kj) {
            bf16x8 ap = *(const bf16x8*)&ps[w*16*LDK + li*LDK + kj*32 + quad*8];
            #pragma unroll
            for (int dj = 0; dj < 4; ++dj) {
                bf16x8 bv = *(const bf16x8*)&vt[(dj*16 + li)*LDK + kj*32 + quad*8];
                oacc[dj] = __builtin_amdgcn_mfma_f32_16x16x32_bf16(ap, bv, oacc[dj], 0, 0, 0);
            }
        }
    }

    float inv[4];
    #pragma unroll
    for (int r = 0; r < 4; ++r) inv[r] = 1.0f / l_run[r];
    #pragma unroll
    for (int dj = 0; dj < 4; ++dj)
        #pragma unroll
        for (int r = 0; r < 4; ++r) {
            int t = qt0w + quad*4 + r;
            ao[((size_t)(b*TT + t))*DIM + h*HD + dj*16 + li] = oacc[dj][r] * inv[r];
        }
}

// ---------------- Kernel D: out = ao @ W_proj + b_proj
template<bool BF>
__global__ __launch_bounds__(256) void proj_kernel(
    const float* __restrict__ ao, const void* __restrict__ Wp,
    const void* __restrict__ bp, void* __restrict__ out,
    const int* __restrict__ flag)
{
    if ((*flag != 0) != BF) return;
    const int tid = threadIdx.x;
    const int row0 = blockIdx.x * 4;
    __shared__ float xs[4][DIM];

    #pragma unroll
    for (int rr = 0; rr < 4; ++rr) {
        float2 v = ((const float2*)(ao + (size_t)(row0 + rr) * DIM))[tid];
        xs[rr][2*tid]   = v.x;
        xs[rr][2*tid+1] = v.y;
    }
    __syncthreads();

    float acc[4][2];
    #pragma unroll
    for (int rr = 0; rr < 4; ++rr) { acc[rr][0] = 0.f; acc[rr][1] = 0.f; }

    for (int k4 = 0; k4 < DIM/4; ++k4) {
        float xb[4][4];
        #pragma unroll
        for (int rr = 0; rr < 4; ++rr) {
            float4 v4 = *(const float4*)&xs[rr][4*k4];
            xb[rr][0] = v4.x; xb[rr][1] = v4.y; xb[rr][2] = v4.z; xb[rr][3] = v4.w;
        }
        #pragma unroll
        for (int u = 0; u < 4; ++u) {
            int k = 4*k4 + u;
            float2 w = ld2<BF>(Wp, (size_t)k * DIM + 2*tid);
            #pragma unroll
            for (int rr = 0; rr < 4; ++rr) {
                acc[rr][0] += xb[rr][u] * w.x;
                acc[rr][1] += xb[rr][u] * w.y;
            }
        }
    }

    float2 bb = ld2<BF>(bp, 2*tid);
    #pragma unroll
    for (int rr = 0; rr < 4; ++rr) {
        st2<BF>(out, (size_t)(row0 + rr) * DIM + 2*tid,
                acc[rr][0] + bb.x, acc[rr][1] + bb.y);
    }
}

extern "C" void kernel_launch(void* const* d_in, const int* in_sizes, int n_in,
                              void* d_out, int out_size, void* d_ws, size_t ws_size,
                              hipStream_t stream)
{
    const void* x     = d_in[0];
    const void* Wqkv  = d_in[1];
    const void* Wproj = d_in[2];
    const void* bproj = d_in[3];

    char* ws = (char*)d_ws;
    const size_t MB = 1024*1024;
    u16*   q16  = (u16*)(ws);                          // 8 MB  [b,h,t,d] bf16
    u16*   vt16 = (u16*)(ws + 8*MB);                   // 8 MB  [b,h,d,t] bf16
    float* ao   = (float*)(ws + 16*MB);                // 16 MB [b,t,dim] f32
    float* qsq  = (float*)(ws + 32*MB);                // 256 KB
    float* asq  = (float*)(ws + 32*MB + 262144);       // 128 B
    u32* bmaxsq = (u32*)(ws + 32*MB + 262144 + 128);   // 16 B
    int* flag   = (int*)(ws + 32*MB + 262144 + 192);   // 4 B

    (void)in_sizes; (void)n_in; (void)out_size; (void)ws_size;

    init_kernel<<<1, 256, 0, stream>>>((const u16*)x, asq, bmaxsq, flag);

    qkv_kernel<true>  <<<NROW/4, 256, 0, stream>>>(x, Wqkv, q16, vt16, bmaxsq, flag);
    qkv_kernel<false> <<<NROW/4, 256, 0, stream>>>(x, Wqkv, q16, vt16, bmaxsq, flag);

    qsq_kernel <<<BH*8, 256, 0, stream>>>(q16, qsq, asq);

    attn_kernel<<<BH*32, 256, 0, stream>>>(q16, vt16, qsq, asq, bmaxsq, ao);

    proj_kernel<true>  <<<NROW/4, 256, 0, stream>>>(ao, Wproj, bproj, d_out, flag);
    proj_kernel<false> <<<NROW/4, 256, 0, stream>>>(ao, Wproj, bproj, d_out, flag);
}

// Round 5
// 488.522 us; speedup vs baseline: 6.9625x; 1.0241x over previous
//
#include <hip/hip_runtime.h>
#include <hip/hip_bf16.h>

#define BB 4
#define TT 2048
#define DIM 512
#define NH 8
#define HD 64
#define NROW (BB*TT)   // 8192
#define BH (BB*NH)     // 32

typedef unsigned short u16;
typedef unsigned int u32;
typedef __attribute__((ext_vector_type(8))) short bf16x8;   // 8 bf16 = 4 VGPRs
typedef __attribute__((ext_vector_type(8))) unsigned short u16x8;
typedef __attribute__((ext_vector_type(4))) float f32x4;
typedef __attribute__((ext_vector_type(4))) unsigned short u16x4;

static __device__ __forceinline__ float bf2f(u16 u) {
    return __uint_as_float(((u32)u) << 16);
}
static __device__ __forceinline__ u16 f2bf(float f) {
    u32 u = __float_as_uint(f);
    u32 r = (u + 0x7FFFu + ((u >> 16) & 1u)) >> 16;
    return (u16)r;
}

template<bool BF>
static __device__ __forceinline__ float2 ld2(const void* p, size_t i) {
    if (BF) { ushort2 v = *(const ushort2*)((const u16*)p + i);
              return make_float2(bf2f(v.x), bf2f(v.y)); }
    else    return *(const float2*)((const float*)p + i);
}
template<bool BF>
static __device__ __forceinline__ float4 ld4(const void* p, size_t i) {
    if (BF) { ushort4 v = *(const ushort4*)((const u16*)p + i);
              return make_float4(bf2f(v.x), bf2f(v.y), bf2f(v.z), bf2f(v.w)); }
    else    return *(const float4*)((const float*)p + i);
}

// ---------------- Kernel 0: detect input dtype + zero accumulators
__global__ __launch_bounds__(256) void init_kernel(
    const u16* __restrict__ xraw, float* __restrict__ asq,
    u32* __restrict__ bmaxsq, int* __restrict__ flag)
{
    const int tid = threadIdx.x;
    if (tid < BH) asq[tid] = 0.0f;
    if (tid >= 32 && tid < 32 + BB) bmaxsq[tid - 32] = 0u;

    float v = bf2f(xraw[2 * tid]);
    float av = fabsf(v);
    int in = (av > 1e-5f && av < 1e5f) ? 1 : 0;
    __shared__ int cnt[256];
    cnt[tid] = in;
    __syncthreads();
    for (int s = 128; s > 0; s >>= 1) {
        if (tid < s) cnt[tid] += cnt[tid + s];
        __syncthreads();
    }
    if (tid == 0) *flag = (cnt[0] > 128) ? 1 : 0;   // 1 = bf16, 0 = f32
}

// ---------------- xsq: per-row ||x||^2 -> block max -> 1 atomicMax per block
template<bool BF>
__global__ __launch_bounds__(256) void xsq_kernel(
    const void* __restrict__ x, u32* __restrict__ bmaxsq,
    const int* __restrict__ flag)
{
    if ((*flag != 0) != BF) return;
    const int tid = threadIdx.x;
    const int row = blockIdx.x * 32 + (tid >> 3);   // 32 rows/block, 8 lanes/row
    const int b = (blockIdx.x * 32) >> 11;
    size_t base = (size_t)row * DIM + (tid & 7) * 64;
    float s = 0.0f;
    #pragma unroll
    for (int j = 0; j < 16; ++j) {
        float4 v = ld4<BF>(x, base + j * 4);
        s += v.x*v.x + v.y*v.y + v.z*v.z + v.w*v.w;
    }
    #pragma unroll
    for (int off = 1; off < 8; off <<= 1) s += __shfl_xor(s, off, 64);
    // every lane now holds its row's full sum; max across wave
    float m = s;
    #pragma unroll
    for (int off = 8; off < 64; off <<= 1) m = fmaxf(m, __shfl_xor(m, off, 64));
    __shared__ float red[4];
    if ((tid & 63) == 0) red[tid >> 6] = m;
    __syncthreads();
    if (tid == 0) {
        float mx = fmaxf(fmaxf(red[0], red[1]), fmaxf(red[2], red[3]));
        atomicMax(&bmaxsq[b], __float_as_uint(mx));
    }
}

// ---------------- transpose (bf16 only): in [K][N] -> out [N][K]
__global__ __launch_bounds__(256) void transpose_kernel(
    const u16* __restrict__ in, u16* __restrict__ outp, int K, int N,
    const int* __restrict__ flag)
{
    if (*flag == 0) return;
    __shared__ u16 t[32][33];
    const int ntiles = N >> 5;
    const int bx = blockIdx.x % ntiles, by = blockIdx.x / ntiles;
    const int n0 = bx * 32, k0 = by * 32;
    const int tx = threadIdx.x & 31, ty = threadIdx.x >> 5;   // 8 rows/pass
    #pragma unroll
    for (int i = 0; i < 32; i += 8)
        t[ty + i][tx] = in[(size_t)(k0 + ty + i) * N + n0 + tx];
    __syncthreads();
    #pragma unroll
    for (int i = 0; i < 32; i += 8)
        outp[(size_t)(n0 + ty + i) * K + k0 + tx] = t[tx][ty + i];
}

// ---------------- MFMA GEMM: qkv = x @ Wqkv (via Wt [1024][512]),
// scatter epilogue -> q bf16 [b,h,t,d], v bf16 [b,h,d,t]. bf16 path only.
#define LDG 72
__global__ __launch_bounds__(256) void qkv_mfma(
    const u16* __restrict__ x, const u16* __restrict__ Wt,
    u16* __restrict__ q16, u16* __restrict__ vt16,
    const int* __restrict__ flag)
{
    if (*flag == 0) return;
    const int tid = threadIdx.x, lane = tid & 63, w = tid >> 6;
    const int li = lane & 15, quad = lane >> 4;
    const int mb = blockIdx.x >> 3, nb = blockIdx.x & 7;   // 64 x 8
    const int row0 = mb * 128, n0 = nb * 128;
    const int b = row0 >> 11;
    const int wm = w >> 1, wn = w & 1;

    __shared__ __align__(16) u16 as[128 * LDG];
    __shared__ __align__(16) u16 bs[128 * LDG];

    f32x4 acc[4][4];
    #pragma unroll
    for (int mi = 0; mi < 4; ++mi)
        #pragma unroll
        for (int ni = 0; ni < 4; ++ni) acc[mi][ni] = f32x4{0.f,0.f,0.f,0.f};

    for (int k0 = 0; k0 < DIM; k0 += 64) {
        __syncthreads();
        #pragma unroll
        for (int it = 0; it < 4; ++it) {
            int id = it * 256 + tid;          // 1024 chunks of 8 elems
            int r = id >> 3, c = id & 7;
            *(bf16x8*)&as[r*LDG + c*8] =
                *(const bf16x8*)(x  + (size_t)(row0 + r)*DIM + k0 + c*8);
            *(bf16x8*)&bs[r*LDG + c*8] =
                *(const bf16x8*)(Wt + (size_t)(n0  + r)*DIM + k0 + c*8);
        }
        __syncthreads();

        bf16x8 af[4][2], bfr[4][2];
        #pragma unroll
        for (int mi = 0; mi < 4; ++mi) {
            const u16* p = &as[(wm*64 + mi*16 + li)*LDG + quad*8];
            af[mi][0] = *(const bf16x8*)p;
            af[mi][1] = *(const bf16x8*)(p + 32);
        }
        #pragma unroll
        for (int ni = 0; ni < 4; ++ni) {
            const u16* p = &bs[(wn*64 + ni*16 + li)*LDG + quad*8];
            bfr[ni][0] = *(const bf16x8*)p;
            bfr[ni][1] = *(const bf16x8*)(p + 32);
        }
        #pragma unroll
        for (int mi = 0; mi < 4; ++mi)
            #pragma unroll
            for (int ni = 0; ni < 4; ++ni) {
                acc[mi][ni] = __builtin_amdgcn_mfma_f32_16x16x32_bf16(
                    af[mi][0], bfr[ni][0], acc[mi][ni], 0, 0, 0);
                acc[mi][ni] = __builtin_amdgcn_mfma_f32_16x16x32_bf16(
                    af[mi][1], bfr[ni][1], acc[mi][ni], 0, 0, 0);
            }
    }

    // epilogue scatter: col = d*16 + kk*8 + h; 16-col tile => constant d
    const int h = li & 7;
    const bool isv = ((li >> 3) & 1) != 0;
    #pragma unroll
    for (int ni = 0; ni < 4; ++ni) {
        int col0 = n0 + wn*64 + ni*16;
        int d = col0 >> 4;
        #pragma unroll
        for (int mi = 0; mi < 4; ++mi) {
            int t0 = (row0 & (TT-1)) + wm*64 + mi*16 + quad*4;
            if (!isv) {
                u16* dst = q16 + ((size_t)(b*NH + h)*TT + t0)*HD + d;
                #pragma unroll
                for (int r = 0; r < 4; ++r)
                    dst[(size_t)r * HD] = f2bf(acc[mi][ni][r]);
            } else {
                u16x4 pk;
                pk.x = f2bf(acc[mi][ni][0]); pk.y = f2bf(acc[mi][ni][1]);
                pk.z = f2bf(acc[mi][ni][2]); pk.w = f2bf(acc[mi][ni][3]);
                *(u16x4*)(vt16 + ((size_t)(b*NH + h)*HD + d)*TT + t0) = pk;
            }
        }
    }
}

// ---------------- MFMA GEMM: out = ao16 @ Wproj + bias (bf16 path)
__global__ __launch_bounds__(256) void proj_mfma(
    const u16* __restrict__ ao16, const u16* __restrict__ Wt,
    const u16* __restrict__ bp, u16* __restrict__ out,
    const int* __restrict__ flag)
{
    if (*flag == 0) return;
    const int tid = threadIdx.x, lane = tid & 63, w = tid >> 6;
    const int li = lane & 15, quad = lane >> 4;
    const int mb = blockIdx.x >> 2, nb = blockIdx.x & 3;   // 64 x 4
    const int row0 = mb * 128, n0 = nb * 128;
    const int wm = w >> 1, wn = w & 1;

    __shared__ __align__(16) u16 as[128 * LDG];
    __shared__ __align__(16) u16 bs[128 * LDG];

    f32x4 acc[4][4];
    #pragma unroll
    for (int mi = 0; mi < 4; ++mi)
        #pragma unroll
        for (int ni = 0; ni < 4; ++ni) acc[mi][ni] = f32x4{0.f,0.f,0.f,0.f};

    for (int k0 = 0; k0 < DIM; k0 += 64) {
        __syncthreads();
        #pragma unroll
        for (int it = 0; it < 4; ++it) {
            int id = it * 256 + tid;
            int r = id >> 3, c = id & 7;
            *(bf16x8*)&as[r*LDG + c*8] =
                *(const bf16x8*)(ao16 + (size_t)(row0 + r)*DIM + k0 + c*8);
            *(bf16x8*)&bs[r*LDG + c*8] =
                *(const bf16x8*)(Wt   + (size_t)(n0  + r)*DIM + k0 + c*8);
        }
        __syncthreads();

        bf16x8 af[4][2], bfr[4][2];
        #pragma unroll
        for (int mi = 0; mi < 4; ++mi) {
            const u16* p = &as[(wm*64 + mi*16 + li)*LDG + quad*8];
            af[mi][0] = *(const bf16x8*)p;
            af[mi][1] = *(const bf16x8*)(p + 32);
        }
        #pragma unroll
        for (int ni = 0; ni < 4; ++ni) {
            const u16* p = &bs[(wn*64 + ni*16 + li)*LDG + quad*8];
            bfr[ni][0] = *(const bf16x8*)p;
            bfr[ni][1] = *(const bf16x8*)(p + 32);
        }
        #pragma unroll
        for (int mi = 0; mi < 4; ++mi)
            #pragma unroll
            for (int ni = 0; ni < 4; ++ni) {
                acc[mi][ni] = __builtin_amdgcn_mfma_f32_16x16x32_bf16(
                    af[mi][0], bfr[ni][0], acc[mi][ni], 0, 0, 0);
                acc[mi][ni] = __builtin_amdgcn_mfma_f32_16x16x32_bf16(
                    af[mi][1], bfr[ni][1], acc[mi][ni], 0, 0, 0);
            }
    }

    #pragma unroll
    for (int ni = 0; ni < 4; ++ni) {
        int col = n0 + wn*64 + ni*16 + li;
        float bias = bf2f(bp[col]);
        #pragma unroll
        for (int mi = 0; mi < 4; ++mi) {
            int r0 = row0 + wm*64 + mi*16 + quad*4;
            #pragma unroll
            for (int r = 0; r < 4; ++r)
                out[(size_t)(r0 + r)*DIM + col] = f2bf(acc[mi][ni][r] + bias);
        }
    }
}

// ---------------- VALU fallback (f32 input path only)
__global__ __launch_bounds__(256) void qkv_valu(
    const float* __restrict__ x, const float* __restrict__ Wqkv,
    u16* __restrict__ q16, u16* __restrict__ vt16,
    const int* __restrict__ flag)
{
    if (*flag != 0) return;
    const int tid = threadIdx.x;
    const int row0 = blockIdx.x * 4;
    const int b = row0 >> 11;
    const int t0g = row0 & (TT - 1);

    __shared__ float xs[4][DIM];
    #pragma unroll
    for (int rr = 0; rr < 4; ++rr) {
        float2 xv = *(const float2*)(x + (size_t)(row0 + rr) * DIM + 2 * tid);
        xs[rr][2*tid]   = xv.x;
        xs[rr][2*tid+1] = xv.y;
    }
    __syncthreads();

    float acc[4][4];
    #pragma unroll
    for (int rr = 0; rr < 4; ++rr)
        #pragma unroll
        for (int i = 0; i < 4; ++i) acc[rr][i] = 0.0f;

    for (int k4 = 0; k4 < DIM/4; ++k4) {
        float xb[4][4];
        #pragma unroll
        for (int rr = 0; rr < 4; ++rr) {
            float4 v4 = *(const float4*)&xs[rr][4*k4];
            xb[rr][0] = v4.x; xb[rr][1] = v4.y; xb[rr][2] = v4.z; xb[rr][3] = v4.w;
        }
        #pragma unroll
        for (int u = 0; u < 4; ++u) {
            int k = 4*k4 + u;
            float4 wv = *(const float4*)(Wqkv + (size_t)k * (2*DIM) + 4*tid);
            #pragma unroll
            for (int rr = 0; rr < 4; ++rr) {
                float xv = xb[rr][u];
                acc[rr][0] += xv * wv.x;
                acc[rr][1] += xv * wv.y;
                acc[rr][2] += xv * wv.z;
                acc[rr][3] += xv * wv.w;
            }
        }
    }

    const int d = tid >> 2;
    const int hbase = 4 * (tid & 1);
    if (((tid >> 1) & 1) == 0) {
        #pragma unroll
        for (int i = 0; i < 4; ++i) {
            int h = hbase + i;
            u16* dst = q16 + ((size_t)(b*NH + h)*TT + t0g)*HD + d;
            #pragma unroll
            for (int rr = 0; rr < 4; ++rr) dst[(size_t)rr * HD] = f2bf(acc[rr][i]);
        }
    } else {
        #pragma unroll
        for (int i = 0; i < 4; ++i) {
            int h = hbase + i;
            u16x4 pk;
            pk.x = f2bf(acc[0][i]); pk.y = f2bf(acc[1][i]);
            pk.z = f2bf(acc[2][i]); pk.w = f2bf(acc[3][i]);
            *(u16x4*)(vt16 + ((size_t)(b*NH + h)*HD + d)*TT + t0g) = pk;
        }
    }
}

__global__ __launch_bounds__(256) void proj_valu(
    const u16* __restrict__ ao16, const float* __restrict__ Wp,
    const float* __restrict__ bp, float* __restrict__ out,
    const int* __restrict__ flag)
{
    if (*flag != 0) return;
    const int tid = threadIdx.x;
    const int row0 = blockIdx.x * 4;
    __shared__ float xs[4][DIM];

    #pragma unroll
    for (int rr = 0; rr < 4; ++rr) {
        float2 v = ld2<true>(ao16, (size_t)(row0 + rr) * DIM + 2 * tid);
        xs[rr][2*tid]   = v.x;
        xs[rr][2*tid+1] = v.y;
    }
    __syncthreads();

    float acc[4][2];
    #pragma unroll
    for (int rr = 0; rr < 4; ++rr) { acc[rr][0] = 0.f; acc[rr][1] = 0.f; }

    for (int k4 = 0; k4 < DIM/4; ++k4) {
        float xb[4][4];
        #pragma unroll
        for (int rr = 0; rr < 4; ++rr) {
            float4 v4 = *(const float4*)&xs[rr][4*k4];
            xb[rr][0] = v4.x; xb[rr][1] = v4.y; xb[rr][2] = v4.z; xb[rr][3] = v4.w;
        }
        #pragma unroll
        for (int u = 0; u < 4; ++u) {
            int k = 4*k4 + u;
            float2 w = *(const float2*)(Wp + (size_t)k * DIM + 2*tid);
            #pragma unroll
            for (int rr = 0; rr < 4; ++rr) {
                acc[rr][0] += xb[rr][u] * w.x;
                acc[rr][1] += xb[rr][u] * w.y;
            }
        }
    }

    float2 bb = *(const float2*)(bp + 2*tid);
    #pragma unroll
    for (int rr = 0; rr < 4; ++rr)
        *(float2*)(out + (size_t)(row0 + rr) * DIM + 2*tid) =
            make_float2(acc[rr][0] + bb.x, acc[rr][1] + bb.y);
}

// ---------------- qsq: qsq[b,h,t] = sum_d q^2 ; asq[b,h] via 1 atomic/block
__global__ __launch_bounds__(256) void qsq_kernel(
    const u16* __restrict__ q16, float* __restrict__ qsq, float* __restrict__ asq)
{
    const int tid = threadIdx.x;
    const int bh = blockIdx.x >> 3;
    const int r0 = (blockIdx.x & 7) * 256;
    const u16* qb = q16 + ((size_t)bh * TT + r0) * HD;

    float tot = 0.0f;
    #pragma unroll
    for (int i = 0; i < 8; ++i) {
        int row = i * 32 + (tid >> 3);
        u16x8 v = *(const u16x8*)(qb + (size_t)row * HD + (tid & 7) * 8);
        float s = 0.0f;
        #pragma unroll
        for (int j = 0; j < 8; ++j) { float f = bf2f(v[j]); s += f * f; }
        tot += s;
        #pragma unroll
        for (int off = 1; off < 8; off <<= 1) s += __shfl_xor(s, off, 64);
        if ((tid & 7) == 0) qsq[(size_t)bh * TT + r0 + row] = s;
    }
    __shared__ float red[4];
    #pragma unroll
    for (int off = 32; off > 0; off >>= 1) tot += __shfl_down(tot, off, 64);
    if ((tid & 63) == 0) red[tid >> 6] = tot;
    __syncthreads();
    if (tid == 0) atomicAdd(&asq[bh], red[0] + red[1] + red[2] + red[3]);
}

// ---------------- flash-style MFMA attention (ao out = bf16)
#define LDK 72
__global__ __launch_bounds__(256) void attn_kernel(
    const u16* __restrict__ q16, const u16* __restrict__ vt16,
    const float* __restrict__ qsq, const float* __restrict__ asq,
    const u32* __restrict__ bmaxsq, u16* __restrict__ ao16)
{
    const int tid = threadIdx.x;
    const int lane = tid & 63, w = tid >> 6;
    const int li = lane & 15, quad = lane >> 4;
    const int bh = blockIdx.x >> 5;
    const int qtile = blockIdx.x & 31;
    const int b = bh >> 3, h = bh & 7;

    __shared__ __align__(16) u16 ks[64 * LDK];
    __shared__ __align__(16) u16 vt[64 * LDK];
    __shared__ __align__(16) u16 ps[4 * 16 * LDK];

    const u16* qg = q16  + (size_t)bh * TT * HD;
    const u16* vg = vt16 + (size_t)bh * HD * TT;
    const float* qsqg = qsq + (size_t)bh * TT;

    float cs;
    {
        float a  = sqrtf(asq[bh]);
        float bm = sqrtf(__uint_as_float(bmaxsq[b]));
        cs = 100.0f / (a * bm + 1e-10f);
    }
    const float c2 = 2.0f * cs;

    const int qt0w = qtile * 64 + w * 16;
    const u16* qr = qg + (size_t)(qt0w + li) * HD + quad * 8;
    bf16x8 a0 = *(const bf16x8*)qr;
    bf16x8 a1 = *(const bf16x8*)(qr + 32);

    float m_run[4] = {-1e30f, -1e30f, -1e30f, -1e30f};
    float l_run[4] = {0.f, 0.f, 0.f, 0.f};
    f32x4 oacc[4];
    #pragma unroll
    for (int dj = 0; dj < 4; ++dj) oacc[dj] = f32x4{0.f, 0.f, 0.f, 0.f};

    for (int s0 = 0; s0 < TT; s0 += 64) {
        __syncthreads();
        #pragma unroll
        for (int it = 0; it < 2; ++it) {
            int u = it * 256 + tid;
            int r = u >> 3, c = u & 7;
            *(bf16x8*)&ks[r*LDK + c*8] =
                *(const bf16x8*)(qg + (size_t)s0*HD + (size_t)u*8);
            *(bf16x8*)&vt[r*LDK + c*8] =
                *(const bf16x8*)(vg + (size_t)r*TT + s0 + c*8);
        }
        __syncthreads();

        float lg[4][4];
        #pragma unroll
        for (int cj = 0; cj < 4; ++cj) {
            const u16* kr = &ks[(cj*16 + li)*LDK + quad*8];
            bf16x8 b0 = *(const bf16x8*)kr;
            bf16x8 b1 = *(const bf16x8*)(kr + 32);
            f32x4 acc = f32x4{0.f, 0.f, 0.f, 0.f};
            acc = __builtin_amdgcn_mfma_f32_16x16x32_bf16(a0, b0, acc, 0, 0, 0);
            acc = __builtin_amdgcn_mfma_f32_16x16x32_bf16(a1, b1, acc, 0, 0, 0);
            float sq = cs * qsqg[s0 + cj*16 + li];
            #pragma unroll
            for (int r = 0; r < 4; ++r) lg[cj][r] = c2 * acc[r] - sq;
        }

        float mt[4];
        #pragma unroll
        for (int r = 0; r < 4; ++r)
            mt[r] = fmaxf(fmaxf(lg[0][r], lg[1][r]), fmaxf(lg[2][r], lg[3][r]));
        #pragma unroll
        for (int off = 1; off < 16; off <<= 1)
            #pragma unroll
            for (int r = 0; r < 4; ++r)
                mt[r] = fmaxf(mt[r], __shfl_xor(mt[r], off, 64));
        float al[4];
        #pragma unroll
        for (int r = 0; r < 4; ++r) {
            float mn = fmaxf(m_run[r], mt[r]);
            al[r] = __expf(m_run[r] - mn);
            m_run[r] = mn;
        }
        float ssum[4] = {0.f, 0.f, 0.f, 0.f};
        #pragma unroll
        for (int cj = 0; cj < 4; ++cj)
            #pragma unroll
            for (int r = 0; r < 4; ++r) {
                float p = __expf(lg[cj][r] - m_run[r]);
                ssum[r] += p;
                ps[w*16*LDK + (quad*4 + r)*LDK + cj*16 + li] = f2bf(p);
            }
        #pragma unroll
        for (int off = 1; off < 16; off <<= 1)
            #pragma unroll
            for (int r = 0; r < 4; ++r)
                ssum[r] += __shfl_xor(ssum[r], off, 64);
        #pragma unroll
        for (int r = 0; r < 4; ++r) l_run[r] = l_run[r]*al[r] + ssum[r];
        #pragma unroll
        for (int dj = 0; dj < 4; ++dj)
            #pragma unroll
            for (int r = 0; r < 4; ++r) oacc[dj][r] *= al[r];

        #pragma unroll
        for (int kj = 0; kj < 2; ++kj) {
            bf16x8 ap = *(const bf16x8*)&ps[w*16*LDK + li*LDK + kj*32 + quad*8];
            #pragma unroll
            for (int dj = 0; dj < 4; ++dj) {
                bf16x8 bv = *(const bf16x8*)&vt[(dj*16 + li)*LDK + kj*32 + quad*8];
                oacc[dj] = __builtin_amdgcn_mfma_f32_16x16x32_bf16(ap, bv, oacc[dj], 0, 0, 0);
            }
        }
    }

    float inv[4];
    #pragma unroll
    for (int r = 0; r < 4; ++r) inv[r] = 1.0f / l_run[r];
    #pragma unroll
    for (int dj = 0; dj < 4; ++dj)
        #pragma unroll
        for (int r = 0; r < 4; ++r) {
            int t = qt0w + quad*4 + r;
            ao16[((size_t)(b*TT + t))*DIM + h*HD + dj*16 + li] =
                f2bf(oacc[dj][r] * inv[r]);
        }
}

extern "C" void kernel_launch(void* const* d_in, const int* in_sizes, int n_in,
                              void* d_out, int out_size, void* d_ws, size_t ws_size,
                              hipStream_t stream)
{
    const void* x     = d_in[0];
    const void* Wqkv  = d_in[1];
    const void* Wproj = d_in[2];
    const void* bproj = d_in[3];

    char* ws = (char*)d_ws;
    const size_t MB = 1024*1024;
    u16*   q16  = (u16*)(ws);                          // 8 MB  [b,h,t,d] bf16
    u16*   vt16 = (u16*)(ws + 8*MB);                   // 8 MB  [b,h,d,t] bf16
    u16*   ao16 = (u16*)(ws + 16*MB);                  // 8 MB  [b,t,dim] bf16
    u16*   Wtq  = (u16*)(ws + 24*MB);                  // 1 MB  [1024][512]
    u16*   Wtp  = (u16*)(ws + 25*MB);                  // 0.5MB [512][512]
    float* qsq  = (float*)(ws + 26*MB);                // 256 KB
    float* asq  = (float*)(ws + 26*MB + 262144);       // 128 B
    u32* bmaxsq = (u32*)(ws + 26*MB + 262144 + 128);   // 16 B
    int* flag   = (int*)(ws + 26*MB + 262144 + 192);   // 4 B

    (void)in_sizes; (void)n_in; (void)out_size; (void)ws_size;

    init_kernel<<<1, 256, 0, stream>>>((const u16*)x, asq, bmaxsq, flag);

    xsq_kernel<true>  <<<NROW/32, 256, 0, stream>>>(x, bmaxsq, flag);
    xsq_kernel<false> <<<NROW/32, 256, 0, stream>>>(x, bmaxsq, flag);

    transpose_kernel<<<(1024/32)*(512/32), 256, 0, stream>>>(
        (const u16*)Wqkv, Wtq, 512, 1024, flag);
    transpose_kernel<<<(512/32)*(512/32), 256, 0, stream>>>(
        (const u16*)Wproj, Wtp, 512, 512, flag);

    qkv_mfma<<<64*8, 256, 0, stream>>>((const u16*)x, Wtq, q16, vt16, flag);
    qkv_valu<<<NROW/4, 256, 0, stream>>>(
        (const float*)x, (const float*)Wqkv, q16, vt16, flag);

    qsq_kernel<<<BH*8, 256, 0, stream>>>(q16, qsq, asq);

    attn_kernel<<<BH*32, 256, 0, stream>>>(q16, vt16, qsq, asq, bmaxsq, ao16);

    proj_mfma<<<64*4, 256, 0, stream>>>(ao16, Wtp, (const u16*)bproj,
                                        (u16*)d_out, flag);
    proj_valu<<<NROW/4, 256, 0, stream>>>(ao16, (const float*)Wproj,
                                          (const float*)bproj, (float*)d_out, flag);
}

// Round 6
// 261.967 us; speedup vs baseline: 12.9839x; 1.8648x over previous
//
#include <hip/hip_runtime.h>
#include <hip/hip_bf16.h>

#define BB 4
#define TT 2048
#define DIM 512
#define NH 8
#define HD 64
#define NROW (BB*TT)   // 8192
#define BH (BB*NH)     // 32

typedef unsigned short u16;
typedef unsigned int u32;
typedef __attribute__((ext_vector_type(8))) short bf16x8;   // 8 bf16 = 4 VGPRs
typedef __attribute__((ext_vector_type(8))) unsigned short u16x8;
typedef __attribute__((ext_vector_type(4))) float f32x4;
typedef __attribute__((ext_vector_type(4))) unsigned short u16x4;

static __device__ __forceinline__ float bf2f(u16 u) {
    return __uint_as_float(((u32)u) << 16);
}
static __device__ __forceinline__ u16 f2bf(float f) {
    u32 u = __float_as_uint(f);
    u32 r = (u + 0x7FFFu + ((u >> 16) & 1u)) >> 16;
    return (u16)r;
}

// ---------------- init: zero atomic accumulators
__global__ __launch_bounds__(64) void init_kernel(
    float* __restrict__ asq, u32* __restrict__ bmaxsq)
{
    const int tid = threadIdx.x;
    if (tid < BH) asq[tid] = 0.0f;
    if (tid >= 32 && tid < 32 + BB) bmaxsq[tid - 32] = 0u;
}

// ---------------- convert_x: x f32 -> bf16, fused row ||x||^2 -> batch max.
// 32 rows/block, 8 lanes/row, 64 elems/lane.
__global__ __launch_bounds__(256) void convert_x(
    const float* __restrict__ x, u16* __restrict__ x16,
    u32* __restrict__ bmaxsq)
{
    const int tid = threadIdx.x;
    const int row = blockIdx.x * 32 + (tid >> 3);
    const int b = (blockIdx.x * 32) >> 11;      // 2048 rows per batch
    const float* xr = x   + (size_t)row * DIM + (tid & 7) * 64;
    u16*        xo  = x16 + (size_t)row * DIM + (tid & 7) * 64;

    float s = 0.0f;
    #pragma unroll
    for (int j = 0; j < 8; ++j) {
        float4 a = *(const float4*)(xr + j*8);
        float4 c = *(const float4*)(xr + j*8 + 4);
        s += a.x*a.x + a.y*a.y + a.z*a.z + a.w*a.w;
        s += c.x*c.x + c.y*c.y + c.z*c.z + c.w*c.w;
        u16x8 pk;
        pk[0]=f2bf(a.x); pk[1]=f2bf(a.y); pk[2]=f2bf(a.z); pk[3]=f2bf(a.w);
        pk[4]=f2bf(c.x); pk[5]=f2bf(c.y); pk[6]=f2bf(c.z); pk[7]=f2bf(c.w);
        *(u16x8*)(xo + j*8) = pk;
    }
    #pragma unroll
    for (int off = 1; off < 8; off <<= 1) s += __shfl_xor(s, off, 64);
    float m = s;
    #pragma unroll
    for (int off = 8; off < 64; off <<= 1) m = fmaxf(m, __shfl_xor(m, off, 64));
    __shared__ float red[4];
    if ((tid & 63) == 0) red[tid >> 6] = m;
    __syncthreads();
    if (tid == 0) {
        float mx = fmaxf(fmaxf(red[0], red[1]), fmaxf(red[2], red[3]));
        atomicMax(&bmaxsq[b], __float_as_uint(mx));
    }
}

// ---------------- wt: W f32 [K][N] -> Wt bf16 [N][K] (convert + transpose)
__global__ __launch_bounds__(256) void wt_kernel(
    const float* __restrict__ in, u16* __restrict__ outp, int K, int N)
{
    __shared__ u16 t[32][33];
    const int ntiles = N >> 5;
    const int bx = blockIdx.x % ntiles, by = blockIdx.x / ntiles;
    const int n0 = bx * 32, k0 = by * 32;
    const int tx = threadIdx.x & 31, ty = threadIdx.x >> 5;   // 8 rows/pass
    #pragma unroll
    for (int i = 0; i < 32; i += 8)
        t[ty + i][tx] = f2bf(in[(size_t)(k0 + ty + i) * N + n0 + tx]);
    __syncthreads();
    #pragma unroll
    for (int i = 0; i < 32; i += 8)
        outp[(size_t)(n0 + ty + i) * K + k0 + tx] = t[tx][ty + i];
}

// ---------------- MFMA GEMM: qkv = x16 @ Wqkv (via Wt [1024][512] bf16),
// scatter epilogue -> q bf16 [b,h,t,d], v bf16 [b,h,d,t].
#define LDG 72
__global__ __launch_bounds__(256) void qkv_mfma(
    const u16* __restrict__ x16, const u16* __restrict__ Wt,
    u16* __restrict__ q16, u16* __restrict__ vt16)
{
    const int tid = threadIdx.x, lane = tid & 63, w = tid >> 6;
    const int li = lane & 15, quad = lane >> 4;
    const int mb = blockIdx.x >> 3, nb = blockIdx.x & 7;   // 64 x 8
    const int row0 = mb * 128, n0 = nb * 128;
    const int b = row0 >> 11;
    const int wm = w >> 1, wn = w & 1;

    __shared__ __align__(16) u16 as[128 * LDG];
    __shared__ __align__(16) u16 bs[128 * LDG];

    f32x4 acc[4][4];
    #pragma unroll
    for (int mi = 0; mi < 4; ++mi)
        #pragma unroll
        for (int ni = 0; ni < 4; ++ni) acc[mi][ni] = f32x4{0.f,0.f,0.f,0.f};

    for (int k0 = 0; k0 < DIM; k0 += 64) {
        __syncthreads();
        #pragma unroll
        for (int it = 0; it < 4; ++it) {
            int id = it * 256 + tid;          // 1024 chunks of 8 elems
            int r = id >> 3, c = id & 7;
            *(bf16x8*)&as[r*LDG + c*8] =
                *(const bf16x8*)(x16 + (size_t)(row0 + r)*DIM + k0 + c*8);
            *(bf16x8*)&bs[r*LDG + c*8] =
                *(const bf16x8*)(Wt  + (size_t)(n0  + r)*DIM + k0 + c*8);
        }
        __syncthreads();

        bf16x8 af[4][2], bfr[4][2];
        #pragma unroll
        for (int mi = 0; mi < 4; ++mi) {
            const u16* p = &as[(wm*64 + mi*16 + li)*LDG + quad*8];
            af[mi][0] = *(const bf16x8*)p;
            af[mi][1] = *(const bf16x8*)(p + 32);
        }
        #pragma unroll
        for (int ni = 0; ni < 4; ++ni) {
            const u16* p = &bs[(wn*64 + ni*16 + li)*LDG + quad*8];
            bfr[ni][0] = *(const bf16x8*)p;
            bfr[ni][1] = *(const bf16x8*)(p + 32);
        }
        #pragma unroll
        for (int mi = 0; mi < 4; ++mi)
            #pragma unroll
            for (int ni = 0; ni < 4; ++ni) {
                acc[mi][ni] = __builtin_amdgcn_mfma_f32_16x16x32_bf16(
                    af[mi][0], bfr[ni][0], acc[mi][ni], 0, 0, 0);
                acc[mi][ni] = __builtin_amdgcn_mfma_f32_16x16x32_bf16(
                    af[mi][1], bfr[ni][1], acc[mi][ni], 0, 0, 0);
            }
    }

    // epilogue scatter: col = d*16 + kk*8 + h; 16-col tile => constant d
    const int h = li & 7;
    const bool isv = ((li >> 3) & 1) != 0;
    #pragma unroll
    for (int ni = 0; ni < 4; ++ni) {
        int col0 = n0 + wn*64 + ni*16;
        int d = col0 >> 4;
        #pragma unroll
        for (int mi = 0; mi < 4; ++mi) {
            int t0 = (row0 & (TT-1)) + wm*64 + mi*16 + quad*4;
            if (!isv) {
                u16* dst = q16 + ((size_t)(b*NH + h)*TT + t0)*HD + d;
                #pragma unroll
                for (int r = 0; r < 4; ++r)
                    dst[(size_t)r * HD] = f2bf(acc[mi][ni][r]);
            } else {
                u16x4 pk;
                pk.x = f2bf(acc[mi][ni][0]); pk.y = f2bf(acc[mi][ni][1]);
                pk.z = f2bf(acc[mi][ni][2]); pk.w = f2bf(acc[mi][ni][3]);
                *(u16x4*)(vt16 + ((size_t)(b*NH + h)*HD + d)*TT + t0) = pk;
            }
        }
    }
}

// ---------------- MFMA GEMM: out(f32) = ao16 @ Wproj + bias(f32)
__global__ __launch_bounds__(256) void proj_mfma(
    const u16* __restrict__ ao16, const u16* __restrict__ Wt,
    const float* __restrict__ bp, float* __restrict__ out)
{
    const int tid = threadIdx.x, lane = tid & 63, w = tid >> 6;
    const int li = lane & 15, quad = lane >> 4;
    const int mb = blockIdx.x >> 2, nb = blockIdx.x & 3;   // 64 x 4
    const int row0 = mb * 128, n0 = nb * 128;
    const int wm = w >> 1, wn = w & 1;

    __shared__ __align__(16) u16 as[128 * LDG];
    __shared__ __align__(16) u16 bs[128 * LDG];

    f32x4 acc[4][4];
    #pragma unroll
    for (int mi = 0; mi < 4; ++mi)
        #pragma unroll
        for (int ni = 0; ni < 4; ++ni) acc[mi][ni] = f32x4{0.f,0.f,0.f,0.f};

    for (int k0 = 0; k0 < DIM; k0 += 64) {
        __syncthreads();
        #pragma unroll
        for (int it = 0; it < 4; ++it) {
            int id = it * 256 + tid;
            int r = id >> 3, c = id & 7;
            *(bf16x8*)&as[r*LDG + c*8] =
                *(const bf16x8*)(ao16 + (size_t)(row0 + r)*DIM + k0 + c*8);
            *(bf16x8*)&bs[r*LDG + c*8] =
                *(const bf16x8*)(Wt   + (size_t)(n0  + r)*DIM + k0 + c*8);
        }
        __syncthreads();

        bf16x8 af[4][2], bfr[4][2];
        #pragma unroll
        for (int mi = 0; mi < 4; ++mi) {
            const u16* p = &as[(wm*64 + mi*16 + li)*LDG + quad*8];
            af[mi][0] = *(const bf16x8*)p;
            af[mi][1] = *(const bf16x8*)(p + 32);
        }
        #pragma unroll
        for (int ni = 0; ni < 4; ++ni) {
            const u16* p = &bs[(wn*64 + ni*16 + li)*LDG + quad*8];
            bfr[ni][0] = *(const bf16x8*)p;
            bfr[ni][1] = *(const bf16x8*)(p + 32);
        }
        #pragma unroll
        for (int mi = 0; mi < 4; ++mi)
            #pragma unroll
            for (int ni = 0; ni < 4; ++ni) {
                acc[mi][ni] = __builtin_amdgcn_mfma_f32_16x16x32_bf16(
                    af[mi][0], bfr[ni][0], acc[mi][ni], 0, 0, 0);
                acc[mi][ni] = __builtin_amdgcn_mfma_f32_16x16x32_bf16(
                    af[mi][1], bfr[ni][1], acc[mi][ni], 0, 0, 0);
            }
    }

    #pragma unroll
    for (int ni = 0; ni < 4; ++ni) {
        int col = n0 + wn*64 + ni*16 + li;
        float bias = bp[col];
        #pragma unroll
        for (int mi = 0; mi < 4; ++mi) {
            int r0 = row0 + wm*64 + mi*16 + quad*4;
            #pragma unroll
            for (int r = 0; r < 4; ++r)
                out[(size_t)(r0 + r)*DIM + col] = acc[mi][ni][r] + bias;
        }
    }
}

// ---------------- qsq: qsq[b,h,t] = sum_d q^2 ; asq[b,h] via 1 atomic/block
__global__ __launch_bounds__(256) void qsq_kernel(
    const u16* __restrict__ q16, float* __restrict__ qsq, float* __restrict__ asq)
{
    const int tid = threadIdx.x;
    const int bh = blockIdx.x >> 3;
    const int r0 = (blockIdx.x & 7) * 256;
    const u16* qb = q16 + ((size_t)bh * TT + r0) * HD;

    float tot = 0.0f;
    #pragma unroll
    for (int i = 0; i < 8; ++i) {
        int row = i * 32 + (tid >> 3);
        u16x8 v = *(const u16x8*)(qb + (size_t)row * HD + (tid & 7) * 8);
        float s = 0.0f;
        #pragma unroll
        for (int j = 0; j < 8; ++j) { float f = bf2f(v[j]); s += f * f; }
        tot += s;
        #pragma unroll
        for (int off = 1; off < 8; off <<= 1) s += __shfl_xor(s, off, 64);
        if ((tid & 7) == 0) qsq[(size_t)bh * TT + r0 + row] = s;
    }
    __shared__ float red[4];
    #pragma unroll
    for (int off = 32; off > 0; off >>= 1) tot += __shfl_down(tot, off, 64);
    if ((tid & 63) == 0) red[tid >> 6] = tot;
    __syncthreads();
    if (tid == 0) atomicAdd(&asq[bh], red[0] + red[1] + red[2] + red[3]);
}

// ---------------- flash-style MFMA attention (ao out = bf16)
#define LDK 72
__global__ __launch_bounds__(256) void attn_kernel(
    const u16* __restrict__ q16, const u16* __restrict__ vt16,
    const float* __restrict__ qsq, const float* __restrict__ asq,
    const u32* __restrict__ bmaxsq, u16* __restrict__ ao16)
{
    const int tid = threadIdx.x;
    const int lane = tid & 63, w = tid >> 6;
    const int li = lane & 15, quad = lane >> 4;
    const int bh = blockIdx.x >> 5;
    const int qtile = blockIdx.x & 31;
    const int b = bh >> 3, h = bh & 7;

    __shared__ __align__(16) u16 ks[64 * LDK];
    __shared__ __align__(16) u16 vt[64 * LDK];
    __shared__ __align__(16) u16 ps[4 * 16 * LDK];

    const u16* qg = q16  + (size_t)bh * TT * HD;
    const u16* vg = vt16 + (size_t)bh * HD * TT;
    const float* qsqg = qsq + (size_t)bh * TT;

    float cs;
    {
        float a  = sqrtf(asq[bh]);
        float bm = sqrtf(__uint_as_float(bmaxsq[b]));
        cs = 100.0f / (a * bm + 1e-10f);
    }
    const float c2 = 2.0f * cs;

    const int qt0w = qtile * 64 + w * 16;
    const u16* qr = qg + (size_t)(qt0w + li) * HD + quad * 8;
    bf16x8 a0 = *(const bf16x8*)qr;
    bf16x8 a1 = *(const bf16x8*)(qr + 32);

    float m_run[4] = {-1e30f, -1e30f, -1e30f, -1e30f};
    float l_run[4] = {0.f, 0.f, 0.f, 0.f};
    f32x4 oacc[4];
    #pragma unroll
    for (int dj = 0; dj < 4; ++dj) oacc[dj] = f32x4{0.f, 0.f, 0.f, 0.f};

    for (int s0 = 0; s0 < TT; s0 += 64) {
        __syncthreads();
        #pragma unroll
        for (int it = 0; it < 2; ++it) {
            int u = it * 256 + tid;
            int r = u >> 3, c = u & 7;
            *(bf16x8*)&ks[r*LDK + c*8] =
                *(const bf16x8*)(qg + (size_t)s0*HD + (size_t)u*8);
            *(bf16x8*)&vt[r*LDK + c*8] =
                *(const bf16x8*)(vg + (size_t)r*TT + s0 + c*8);
        }
        __syncthreads();

        float lg[4][4];
        #pragma unroll
        for (int cj = 0; cj < 4; ++cj) {
            const u16* kr = &ks[(cj*16 + li)*LDK + quad*8];
            bf16x8 b0 = *(const bf16x8*)kr;
            bf16x8 b1 = *(const bf16x8*)(kr + 32);
            f32x4 acc = f32x4{0.f, 0.f, 0.f, 0.f};
            acc = __builtin_amdgcn_mfma_f32_16x16x32_bf16(a0, b0, acc, 0, 0, 0);
            acc = __builtin_amdgcn_mfma_f32_16x16x32_bf16(a1, b1, acc, 0, 0, 0);
            float sq = cs * qsqg[s0 + cj*16 + li];
            #pragma unroll
            for (int r = 0; r < 4; ++r) lg[cj][r] = c2 * acc[r] - sq;
        }

        float mt[4];
        #pragma unroll
        for (int r = 0; r < 4; ++r)
            mt[r] = fmaxf(fmaxf(lg[0][r], lg[1][r]), fmaxf(lg[2][r], lg[3][r]));
        #pragma unroll
        for (int off = 1; off < 16; off <<= 1)
            #pragma unroll
            for (int r = 0; r < 4; ++r)
                mt[r] = fmaxf(mt[r], __shfl_xor(mt[r], off, 64));
        float al[4];
        #pragma unroll
        for (int r = 0; r < 4; ++r) {
            float mn = fmaxf(m_run[r], mt[r]);
            al[r] = __expf(m_run[r] - mn);
            m_run[r] = mn;
        }
        float ssum[4] = {0.f, 0.f, 0.f, 0.f};
        #pragma unroll
        for (int cj = 0; cj < 4; ++cj)
            #pragma unroll
            for (int r = 0; r < 4; ++r) {
                float p = __expf(lg[cj][r] - m_run[r]);
                ssum[r] += p;
                ps[w*16*LDK + (quad*4 + r)*LDK + cj*16 + li] = f2bf(p);
            }
        #pragma unroll
        for (int off = 1; off < 16; off <<= 1)
            #pragma unroll
            for (int r = 0; r < 4; ++r)
                ssum[r] += __shfl_xor(ssum[r], off, 64);
        #pragma unroll
        for (int r = 0; r < 4; ++r) l_run[r] = l_run[r]*al[r] + ssum[r];
        #pragma unroll
        for (int dj = 0; dj < 4; ++dj)
            #pragma unroll
            for (int r = 0; r < 4; ++r) oacc[dj][r] *= al[r];

        #pragma unroll
        for (int kj = 0; kj < 2; ++kj) {
            bf16x8 ap = *(const bf16x8*)&ps[w*16*LDK + li*LDK + kj*32 + quad*8];
            #pragma unroll
            for (int dj = 0; dj < 4; ++dj) {
                bf16x8 bv = *(const bf16x8*)&vt[(dj*16 + li)*LDK + kj*32 + quad*8];
                oacc[dj] = __builtin_amdgcn_mfma_f32_16x16x32_bf16(ap, bv, oacc[dj], 0, 0, 0);
            }
        }
    }

    float inv[4];
    #pragma unroll
    for (int r = 0; r < 4; ++r) inv[r] = 1.0f / l_run[r];
    #pragma unroll
    for (int dj = 0; dj < 4; ++dj)
        #pragma unroll
        for (int r = 0; r < 4; ++r) {
            int t = qt0w + quad*4 + r;
            ao16[((size_t)(b*TT + t))*DIM + h*HD + dj*16 + li] =
                f2bf(oacc[dj][r] * inv[r]);
        }
}

extern "C" void kernel_launch(void* const* d_in, const int* in_sizes, int n_in,
                              void* d_out, int out_size, void* d_ws, size_t ws_size,
                              hipStream_t stream)
{
    const float* x     = (const float*)d_in[0];   // [4,2048,512] f32
    const float* Wqkv  = (const float*)d_in[1];   // [512,1024]  f32
    const float* Wproj = (const float*)d_in[2];   // [512,512]   f32
    const float* bproj = (const float*)d_in[3];   // [512]       f32
    float* out = (float*)d_out;                   // [4,2048,512] f32

    char* ws = (char*)d_ws;
    const size_t MB = 1024*1024;
    u16*   q16  = (u16*)(ws);                          // 8 MB  [b,h,t,d] bf16
    u16*   vt16 = (u16*)(ws + 8*MB);                   // 8 MB  [b,h,d,t] bf16
    u16*   ao16 = (u16*)(ws + 16*MB);                  // 8 MB  [b,t,dim] bf16
    u16*   x16  = (u16*)(ws + 24*MB);                  // 8 MB  [b,t,dim] bf16
    u16*   Wtq  = (u16*)(ws + 32*MB);                  // 1 MB  [1024][512]
    u16*   Wtp  = (u16*)(ws + 33*MB);                  // 0.5MB [512][512]
    float* qsq  = (float*)(ws + 34*MB);                // 256 KB
    float* asq  = (float*)(ws + 34*MB + 262144);       // 128 B
    u32* bmaxsq = (u32*)(ws + 34*MB + 262144 + 128);   // 16 B

    (void)in_sizes; (void)n_in; (void)out_size; (void)ws_size;

    init_kernel<<<1, 64, 0, stream>>>(asq, bmaxsq);

    convert_x<<<NROW/32, 256, 0, stream>>>(x, x16, bmaxsq);

    wt_kernel<<<(1024/32)*(512/32), 256, 0, stream>>>(Wqkv, Wtq, 512, 1024);
    wt_kernel<<<(512/32)*(512/32),  256, 0, stream>>>(Wproj, Wtp, 512, 512);

    qkv_mfma<<<64*8, 256, 0, stream>>>(x16, Wtq, q16, vt16);

    qsq_kernel<<<BH*8, 256, 0, stream>>>(q16, qsq, asq);

    attn_kernel<<<BH*32, 256, 0, stream>>>(q16, vt16, qsq, asq, bmaxsq, ao16);

    proj_mfma<<<64*4, 256, 0, stream>>>(ao16, Wtp, bproj, out);
}

// Round 7
// 252.022 us; speedup vs baseline: 13.4962x; 1.0395x over previous
//
#include <hip/hip_runtime.h>
#include <hip/hip_bf16.h>

#define BB 4
#define TT 2048
#define DIM 512
#define NH 8
#define HD 64
#define NROW (BB*TT)   // 8192
#define BH (BB*NH)     // 32

typedef unsigned short u16;
typedef unsigned int u32;
typedef __attribute__((ext_vector_type(8))) short bf16x8;   // 8 bf16 = 4 VGPRs
typedef __attribute__((ext_vector_type(8))) unsigned short u16x8;
typedef __attribute__((ext_vector_type(4))) float f32x4;
typedef __attribute__((ext_vector_type(4))) unsigned short u16x4;

static __device__ __forceinline__ float bf2f(u16 u) {
    return __uint_as_float(((u32)u) << 16);
}
static __device__ __forceinline__ u16 f2bf(float f) {
    u32 u = __float_as_uint(f);
    u32 r = (u + 0x7FFFu + ((u >> 16) & 1u)) >> 16;
    return (u16)r;
}

// ---------------- init: zero atomic accumulators
__global__ __launch_bounds__(64) void init_kernel(
    float* __restrict__ asq, u32* __restrict__ bmaxsq)
{
    const int tid = threadIdx.x;
    if (tid < BH) asq[tid] = 0.0f;
    if (tid >= 32 && tid < 32 + BB) bmaxsq[tid - 32] = 0u;
}

// ---------------- convert_x: x f32 -> bf16, fused row ||x||^2 -> batch max.
__global__ __launch_bounds__(256) void convert_x(
    const float* __restrict__ x, u16* __restrict__ x16,
    u32* __restrict__ bmaxsq)
{
    const int tid = threadIdx.x;
    const int row = blockIdx.x * 32 + (tid >> 3);
    const int b = (blockIdx.x * 32) >> 11;      // 2048 rows per batch
    const float* xr = x   + (size_t)row * DIM + (tid & 7) * 64;
    u16*        xo  = x16 + (size_t)row * DIM + (tid & 7) * 64;

    float s = 0.0f;
    #pragma unroll
    for (int j = 0; j < 8; ++j) {
        float4 a = *(const float4*)(xr + j*8);
        float4 c = *(const float4*)(xr + j*8 + 4);
        s += a.x*a.x + a.y*a.y + a.z*a.z + a.w*a.w;
        s += c.x*c.x + c.y*c.y + c.z*c.z + c.w*c.w;
        u16x8 pk;
        pk[0]=f2bf(a.x); pk[1]=f2bf(a.y); pk[2]=f2bf(a.z); pk[3]=f2bf(a.w);
        pk[4]=f2bf(c.x); pk[5]=f2bf(c.y); pk[6]=f2bf(c.z); pk[7]=f2bf(c.w);
        *(u16x8*)(xo + j*8) = pk;
    }
    #pragma unroll
    for (int off = 1; off < 8; off <<= 1) s += __shfl_xor(s, off, 64);
    float m = s;
    #pragma unroll
    for (int off = 8; off < 64; off <<= 1) m = fmaxf(m, __shfl_xor(m, off, 64));
    __shared__ float red[4];
    if ((tid & 63) == 0) red[tid >> 6] = m;
    __syncthreads();
    if (tid == 0) {
        float mx = fmaxf(fmaxf(red[0], red[1]), fmaxf(red[2], red[3]));
        atomicMax(&bmaxsq[b], __float_as_uint(mx));
    }
}

// ---------------- wt: W f32 [K][N] -> Wt bf16 [N][K] (convert + transpose)
__global__ __launch_bounds__(256) void wt_kernel(
    const float* __restrict__ in, u16* __restrict__ outp, int K, int N)
{
    __shared__ u16 t[32][33];
    const int ntiles = N >> 5;
    const int bx = blockIdx.x % ntiles, by = blockIdx.x / ntiles;
    const int n0 = bx * 32, k0 = by * 32;
    const int tx = threadIdx.x & 31, ty = threadIdx.x >> 5;   // 8 rows/pass
    #pragma unroll
    for (int i = 0; i < 32; i += 8)
        t[ty + i][tx] = f2bf(in[(size_t)(k0 + ty + i) * N + n0 + tx]);
    __syncthreads();
    #pragma unroll
    for (int i = 0; i < 32; i += 8)
        outp[(size_t)(n0 + ty + i) * K + k0 + tx] = t[tx][ty + i];
}

// ---------------- MFMA GEMM: qkv = x16 @ Wqkv (via Wt [1024][512] bf16),
// scatter epilogue -> q bf16 [b,h,t,d], v bf16 [b,h,d,t].
#define LDG 72
__global__ __launch_bounds__(256) void qkv_mfma(
    const u16* __restrict__ x16, const u16* __restrict__ Wt,
    u16* __restrict__ q16, u16* __restrict__ vt16)
{
    const int tid = threadIdx.x, lane = tid & 63, w = tid >> 6;
    const int li = lane & 15, quad = lane >> 4;
    const int mb = blockIdx.x >> 3, nb = blockIdx.x & 7;   // 64 x 8
    const int row0 = mb * 128, n0 = nb * 128;
    const int b = row0 >> 11;
    const int wm = w >> 1, wn = w & 1;

    __shared__ __align__(16) u16 as[128 * LDG];
    __shared__ __align__(16) u16 bs[128 * LDG];

    f32x4 acc[4][4];
    #pragma unroll
    for (int mi = 0; mi < 4; ++mi)
        #pragma unroll
        for (int ni = 0; ni < 4; ++ni) acc[mi][ni] = f32x4{0.f,0.f,0.f,0.f};

    for (int k0 = 0; k0 < DIM; k0 += 64) {
        __syncthreads();
        #pragma unroll
        for (int it = 0; it < 4; ++it) {
            int id = it * 256 + tid;          // 1024 chunks of 8 elems
            int r = id >> 3, c = id & 7;
            *(bf16x8*)&as[r*LDG + c*8] =
                *(const bf16x8*)(x16 + (size_t)(row0 + r)*DIM + k0 + c*8);
            *(bf16x8*)&bs[r*LDG + c*8] =
                *(const bf16x8*)(Wt  + (size_t)(n0  + r)*DIM + k0 + c*8);
        }
        __syncthreads();

        bf16x8 af[4][2], bfr[4][2];
        #pragma unroll
        for (int mi = 0; mi < 4; ++mi) {
            const u16* p = &as[(wm*64 + mi*16 + li)*LDG + quad*8];
            af[mi][0] = *(const bf16x8*)p;
            af[mi][1] = *(const bf16x8*)(p + 32);
        }
        #pragma unroll
        for (int ni = 0; ni < 4; ++ni) {
            const u16* p = &bs[(wn*64 + ni*16 + li)*LDG + quad*8];
            bfr[ni][0] = *(const bf16x8*)p;
            bfr[ni][1] = *(const bf16x8*)(p + 32);
        }
        #pragma unroll
        for (int mi = 0; mi < 4; ++mi)
            #pragma unroll
            for (int ni = 0; ni < 4; ++ni) {
                acc[mi][ni] = __builtin_amdgcn_mfma_f32_16x16x32_bf16(
                    af[mi][0], bfr[ni][0], acc[mi][ni], 0, 0, 0);
                acc[mi][ni] = __builtin_amdgcn_mfma_f32_16x16x32_bf16(
                    af[mi][1], bfr[ni][1], acc[mi][ni], 0, 0, 0);
            }
    }

    // epilogue scatter: col = d*16 + kk*8 + h; 16-col tile => constant d
    const int h = li & 7;
    const bool isv = ((li >> 3) & 1) != 0;
    #pragma unroll
    for (int ni = 0; ni < 4; ++ni) {
        int col0 = n0 + wn*64 + ni*16;
        int d = col0 >> 4;
        #pragma unroll
        for (int mi = 0; mi < 4; ++mi) {
            int t0 = (row0 & (TT-1)) + wm*64 + mi*16 + quad*4;
            if (!isv) {
                u16* dst = q16 + ((size_t)(b*NH + h)*TT + t0)*HD + d;
                #pragma unroll
                for (int r = 0; r < 4; ++r)
                    dst[(size_t)r * HD] = f2bf(acc[mi][ni][r]);
            } else {
                u16x4 pk;
                pk.x = f2bf(acc[mi][ni][0]); pk.y = f2bf(acc[mi][ni][1]);
                pk.z = f2bf(acc[mi][ni][2]); pk.w = f2bf(acc[mi][ni][3]);
                *(u16x4*)(vt16 + ((size_t)(b*NH + h)*HD + d)*TT + t0) = pk;
            }
        }
    }
}

// ---------------- MFMA GEMM: out(f32) = ao16 @ Wproj + bias(f32)
__global__ __launch_bounds__(256) void proj_mfma(
    const u16* __restrict__ ao16, const u16* __restrict__ Wt,
    const float* __restrict__ bp, float* __restrict__ out)
{
    const int tid = threadIdx.x, lane = tid & 63, w = tid >> 6;
    const int li = lane & 15, quad = lane >> 4;
    const int mb = blockIdx.x >> 2, nb = blockIdx.x & 3;   // 64 x 4
    const int row0 = mb * 128, n0 = nb * 128;
    const int wm = w >> 1, wn = w & 1;

    __shared__ __align__(16) u16 as[128 * LDG];
    __shared__ __align__(16) u16 bs[128 * LDG];

    f32x4 acc[4][4];
    #pragma unroll
    for (int mi = 0; mi < 4; ++mi)
        #pragma unroll
        for (int ni = 0; ni < 4; ++ni) acc[mi][ni] = f32x4{0.f,0.f,0.f,0.f};

    for (int k0 = 0; k0 < DIM; k0 += 64) {
        __syncthreads();
        #pragma unroll
        for (int it = 0; it < 4; ++it) {
            int id = it * 256 + tid;
            int r = id >> 3, c = id & 7;
            *(bf16x8*)&as[r*LDG + c*8] =
                *(const bf16x8*)(ao16 + (size_t)(row0 + r)*DIM + k0 + c*8);
            *(bf16x8*)&bs[r*LDG + c*8] =
                *(const bf16x8*)(Wt   + (size_t)(n0  + r)*DIM + k0 + c*8);
        }
        __syncthreads();

        bf16x8 af[4][2], bfr[4][2];
        #pragma unroll
        for (int mi = 0; mi < 4; ++mi) {
            const u16* p = &as[(wm*64 + mi*16 + li)*LDG + quad*8];
            af[mi][0] = *(const bf16x8*)p;
            af[mi][1] = *(const bf16x8*)(p + 32);
        }
        #pragma unroll
        for (int ni = 0; ni < 4; ++ni) {
            const u16* p = &bs[(wn*64 + ni*16 + li)*LDG + quad*8];
            bfr[ni][0] = *(const bf16x8*)p;
            bfr[ni][1] = *(const bf16x8*)(p + 32);
        }
        #pragma unroll
        for (int mi = 0; mi < 4; ++mi)
            #pragma unroll
            for (int ni = 0; ni < 4; ++ni) {
                acc[mi][ni] = __builtin_amdgcn_mfma_f32_16x16x32_bf16(
                    af[mi][0], bfr[ni][0], acc[mi][ni], 0, 0, 0);
                acc[mi][ni] = __builtin_amdgcn_mfma_f32_16x16x32_bf16(
                    af[mi][1], bfr[ni][1], acc[mi][ni], 0, 0, 0);
            }
    }

    #pragma unroll
    for (int ni = 0; ni < 4; ++ni) {
        int col = n0 + wn*64 + ni*16 + li;
        float bias = bp[col];
        #pragma unroll
        for (int mi = 0; mi < 4; ++mi) {
            int r0 = row0 + wm*64 + mi*16 + quad*4;
            #pragma unroll
            for (int r = 0; r < 4; ++r)
                out[(size_t)(r0 + r)*DIM + col] = acc[mi][ni][r] + bias;
        }
    }
}

// ---------------- qsq: qsq[b,h,t] = sum_d q^2 ; asq[b,h] via 1 atomic/block
__global__ __launch_bounds__(256) void qsq_kernel(
    const u16* __restrict__ q16, float* __restrict__ qsq, float* __restrict__ asq)
{
    const int tid = threadIdx.x;
    const int bh = blockIdx.x >> 3;
    const int r0 = (blockIdx.x & 7) * 256;
    const u16* qb = q16 + ((size_t)bh * TT + r0) * HD;

    float tot = 0.0f;
    #pragma unroll
    for (int i = 0; i < 8; ++i) {
        int row = i * 32 + (tid >> 3);
        u16x8 v = *(const u16x8*)(qb + (size_t)row * HD + (tid & 7) * 8);
        float s = 0.0f;
        #pragma unroll
        for (int j = 0; j < 8; ++j) { float f = bf2f(v[j]); s += f * f; }
        tot += s;
        #pragma unroll
        for (int off = 1; off < 8; off <<= 1) s += __shfl_xor(s, off, 64);
        if ((tid & 7) == 0) qsq[(size_t)bh * TT + r0 + row] = s;
    }
    __shared__ float red[4];
    #pragma unroll
    for (int off = 32; off > 0; off >>= 1) tot += __shfl_down(tot, off, 64);
    if ((tid & 63) == 0) red[tid >> 6] = tot;
    __syncthreads();
    if (tid == 0) atomicAdd(&asq[bh], red[0] + red[1] + red[2] + red[3]);
}

// ---------------- flash-style MFMA attention, KNOWN-MAX softmax.
// score = -cs*||q_t - q_s||^2 <= 0 with exact max 0 at s=t, so the shifted
// logit's row max is cs*qsq_t -- known a priori. No online rescaling, no
// per-tile reductions; one 16-lane sum reduce at the end. exp2-domain
// (v_exp_f32 is native exp2): p = exp2(c2*dot - cf*qsq_s - cf*qsq_t).
#define LDK 72
__global__ __launch_bounds__(256) void attn_kernel(
    const u16* __restrict__ q16, const u16* __restrict__ vt16,
    const float* __restrict__ qsq, const float* __restrict__ asq,
    const u32* __restrict__ bmaxsq, u16* __restrict__ ao16)
{
    const int tid = threadIdx.x;
    const int lane = tid & 63, w = tid >> 6;
    const int li = lane & 15, quad = lane >> 4;
    const int bh = blockIdx.x >> 5;
    const int qtile = blockIdx.x & 31;
    const int b = bh >> 3, h = bh & 7;

    __shared__ __align__(16) u16 ks[64 * LDK];
    __shared__ __align__(16) u16 vt[64 * LDK];
    __shared__ __align__(16) u16 ps[4 * 16 * LDK];

    const u16* qg = q16  + (size_t)bh * TT * HD;
    const u16* vg = vt16 + (size_t)bh * HD * TT;
    const float* qsqg = qsq + (size_t)bh * TT;

    float cf;   // 100 * log2(e) / (a * bmax + eps)
    {
        float a  = sqrtf(asq[bh]);
        float bm = sqrtf(__uint_as_float(bmaxsq[b]));
        cf = (100.0f * 1.44269504089f) / (a * bm + 1e-10f);
    }
    const float c2 = 2.0f * cf;

    const int qt0w = qtile * 64 + w * 16;
    const u16* qr = qg + (size_t)(qt0w + li) * HD + quad * 8;
    bf16x8 a0 = *(const bf16x8*)qr;
    bf16x8 a1 = *(const bf16x8*)(qr + 32);

    // exact row max (log2 domain): cf * qsq_t for this lane's 4 rows
    float sqrow[4];
    #pragma unroll
    for (int r = 0; r < 4; ++r) sqrow[r] = cf * qsqg[qt0w + quad*4 + r];

    float ssum[4] = {0.f, 0.f, 0.f, 0.f};
    f32x4 oacc[4];
    #pragma unroll
    for (int dj = 0; dj < 4; ++dj) oacc[dj] = f32x4{0.f, 0.f, 0.f, 0.f};

    for (int s0 = 0; s0 < TT; s0 += 64) {
        __syncthreads();
        #pragma unroll
        for (int it = 0; it < 2; ++it) {
            int u = it * 256 + tid;
            int r = u >> 3, c = u & 7;
            *(bf16x8*)&ks[r*LDK + c*8] =
                *(const bf16x8*)(qg + (size_t)s0*HD + (size_t)u*8);
            *(bf16x8*)&vt[r*LDK + c*8] =
                *(const bf16x8*)(vg + (size_t)r*TT + s0 + c*8);
        }
        __syncthreads();

        #pragma unroll
        for (int cj = 0; cj < 4; ++cj) {
            const u16* kr = &ks[(cj*16 + li)*LDK + quad*8];
            bf16x8 b0 = *(const bf16x8*)kr;
            bf16x8 b1 = *(const bf16x8*)(kr + 32);
            f32x4 acc = f32x4{0.f, 0.f, 0.f, 0.f};
            acc = __builtin_amdgcn_mfma_f32_16x16x32_bf16(a0, b0, acc, 0, 0, 0);
            acc = __builtin_amdgcn_mfma_f32_16x16x32_bf16(a1, b1, acc, 0, 0, 0);
            float sqc = cf * qsqg[s0 + cj*16 + li];
            #pragma unroll
            for (int r = 0; r < 4; ++r) {
                float p = exp2f(c2*acc[r] - sqc - sqrow[r]);
                ssum[r] += p;
                ps[w*16*LDK + (quad*4 + r)*LDK + cj*16 + li] = f2bf(p);
            }
        }

        #pragma unroll
        for (int kj = 0; kj < 2; ++kj) {
            bf16x8 ap = *(const bf16x8*)&ps[w*16*LDK + li*LDK + kj*32 + quad*8];
            #pragma unroll
            for (int dj = 0; dj < 4; ++dj) {
                bf16x8 bv = *(const bf16x8*)&vt[(dj*16 + li)*LDK + kj*32 + quad*8];
                oacc[dj] = __builtin_amdgcn_mfma_f32_16x16x32_bf16(ap, bv, oacc[dj], 0, 0, 0);
            }
        }
    }

    // single end-of-kernel row-sum reduce across the 16 li lanes
    #pragma unroll
    for (int off = 1; off < 16; off <<= 1)
        #pragma unroll
        for (int r = 0; r < 4; ++r)
            ssum[r] += __shfl_xor(ssum[r], off, 64);

    float inv[4];
    #pragma unroll
    for (int r = 0; r < 4; ++r) inv[r] = 1.0f / ssum[r];
    #pragma unroll
    for (int dj = 0; dj < 4; ++dj)
        #pragma unroll
        for (int r = 0; r < 4; ++r) {
            int t = qt0w + quad*4 + r;
            ao16[((size_t)(b*TT + t))*DIM + h*HD + dj*16 + li] =
                f2bf(oacc[dj][r] * inv[r]);
        }
}

extern "C" void kernel_launch(void* const* d_in, const int* in_sizes, int n_in,
                              void* d_out, int out_size, void* d_ws, size_t ws_size,
                              hipStream_t stream)
{
    const float* x     = (const float*)d_in[0];   // [4,2048,512] f32
    const float* Wqkv  = (const float*)d_in[1];   // [512,1024]  f32
    const float* Wproj = (const float*)d_in[2];   // [512,512]   f32
    const float* bproj = (const float*)d_in[3];   // [512]       f32
    float* out = (float*)d_out;                   // [4,2048,512] f32

    char* ws = (char*)d_ws;
    const size_t MB = 1024*1024;
    u16*   q16  = (u16*)(ws);                          // 8 MB  [b,h,t,d] bf16
    u16*   vt16 = (u16*)(ws + 8*MB);                   // 8 MB  [b,h,d,t] bf16
    u16*   ao16 = (u16*)(ws + 16*MB);                  // 8 MB  [b,t,dim] bf16
    u16*   x16  = (u16*)(ws + 24*MB);                  // 8 MB  [b,t,dim] bf16
    u16*   Wtq  = (u16*)(ws + 32*MB);                  // 1 MB  [1024][512]
    u16*   Wtp  = (u16*)(ws + 33*MB);                  // 0.5MB [512][512]
    float* qsq  = (float*)(ws + 34*MB);                // 256 KB
    float* asq  = (float*)(ws + 34*MB + 262144);       // 128 B
    u32* bmaxsq = (u32*)(ws + 34*MB + 262144 + 128);   // 16 B

    (void)in_sizes; (void)n_in; (void)out_size; (void)ws_size;

    init_kernel<<<1, 64, 0, stream>>>(asq, bmaxsq);

    convert_x<<<NROW/32, 256, 0, stream>>>(x, x16, bmaxsq);

    wt_kernel<<<(1024/32)*(512/32), 256, 0, stream>>>(Wqkv, Wtq, 512, 1024);
    wt_kernel<<<(512/32)*(512/32),  256, 0, stream>>>(Wproj, Wtp, 512, 512);

    qkv_mfma<<<64*8, 256, 0, stream>>>(x16, Wtq, q16, vt16);

    qsq_kernel<<<BH*8, 256, 0, stream>>>(q16, qsq, asq);

    attn_kernel<<<BH*32, 256, 0, stream>>>(q16, vt16, qsq, asq, bmaxsq, ao16);

    proj_mfma<<<64*4, 256, 0, stream>>>(ao16, Wtp, bproj, out);
}